// Round 8
// baseline (789.786 us; speedup 1.0000x reference)
//
#include <hip/hip_runtime.h>
#include <math.h>

// Problem constants (B=2, T=2048, D=512, H=8, hd=64, K=16, DEPTH=3)
#define TSEQ   2048
#define DM     512
#define NH     8
#define HD     64
#define KATT   16
#define NDEPTH 3
#define MROWS  4096   // B*T

typedef __attribute__((ext_vector_type(8))) short bf16x8;
typedef __attribute__((ext_vector_type(8))) unsigned short u16x8;
typedef __attribute__((ext_vector_type(4))) float f32x4;

// f32 -> bf16 (round-to-nearest-even), bit-level
static __device__ __forceinline__ unsigned short f2b(float f) {
    unsigned int u = __float_as_uint(f);
    unsigned int r = (u + 0x7fffu + ((u >> 16) & 1u)) >> 16;
    return (unsigned short)r;
}
// bf16 bits -> f32
static __device__ __forceinline__ float b2f(unsigned short s) {
    return __uint_as_float((unsigned int)s << 16);
}

// ---------------------------------------------------------------------------
// Weight prep: W f32 [K x N] (per depth) -> Wt bf16 [N x K]. grid.z = depth.
// ---------------------------------------------------------------------------
__global__ __launch_bounds__(256) void transpose_w_kernel(
    const float* __restrict__ W, unsigned short* __restrict__ Wt, int Kd, int Nd)
{
    __shared__ float tile[32][33];
    const int n0 = blockIdx.x * 32, k0 = blockIdx.y * 32;
    const size_t off = (size_t)blockIdx.z * Kd * Nd;
    const float* Wd = W + off;
    unsigned short* Wtd = Wt + off;
    const int tx = threadIdx.x, ty = threadIdx.y;
#pragma unroll
    for (int r = 0; r < 32; r += 8)
        tile[ty + r][tx] = Wd[(size_t)(k0 + ty + r) * Nd + (n0 + tx)];
    __syncthreads();
#pragma unroll
    for (int r = 0; r < 32; r += 8)
        Wtd[(size_t)(n0 + ty + r) * Kd + (k0 + tx)] = f2b(tile[tx][ty + r]);
}

// ---------------------------------------------------------------------------
// LayerNorm: x f32 [4096 x 512] -> h bf16 [4096 x 512]. One wave per row.
// (only used for depth-0 LN1; later LNs are fused into reduce_kernel)
// ---------------------------------------------------------------------------
__global__ __launch_bounds__(256) void ln_kernel(
    const float* __restrict__ x, const float* __restrict__ sc,
    const float* __restrict__ bi, unsigned short* __restrict__ h)
{
    const int wid  = blockIdx.x * 4 + (threadIdx.x >> 6);
    const int lane = threadIdx.x & 63;
    const float* xr = x + (size_t)wid * DM;
    const float4 v0 = *(const float4*)&xr[lane * 4];
    const float4 v1 = *(const float4*)&xr[256 + lane * 4];
    float s = v0.x + v0.y + v0.z + v0.w + v1.x + v1.y + v1.z + v1.w;
    float q = v0.x*v0.x + v0.y*v0.y + v0.z*v0.z + v0.w*v0.w
            + v1.x*v1.x + v1.y*v1.y + v1.z*v1.z + v1.w*v1.w;
#pragma unroll
    for (int off = 32; off; off >>= 1) {
        s += __shfl_xor(s, off, 64);
        q += __shfl_xor(q, off, 64);
    }
    const float mean = s * (1.0f / DM);
    const float var  = q * (1.0f / DM) - mean * mean;
    const float rs   = rsqrtf(var + 1e-5f);
    unsigned short* hr = h + (size_t)wid * DM;
    const int c0 = lane * 4, c1 = 256 + lane * 4;
    ushort4 o0, o1;
    o0.x = f2b((v0.x - mean) * rs * sc[c0+0] + bi[c0+0]);
    o0.y = f2b((v0.y - mean) * rs * sc[c0+1] + bi[c0+1]);
    o0.z = f2b((v0.z - mean) * rs * sc[c0+2] + bi[c0+2]);
    o0.w = f2b((v0.w - mean) * rs * sc[c0+3] + bi[c0+3]);
    o1.x = f2b((v1.x - mean) * rs * sc[c1+0] + bi[c1+0]);
    o1.y = f2b((v1.y - mean) * rs * sc[c1+1] + bi[c1+1]);
    o1.z = f2b((v1.z - mean) * rs * sc[c1+2] + bi[c1+2]);
    o1.w = f2b((v1.w - mean) * rs * sc[c1+3] + bi[c1+3]);
    *(ushort4*)&hr[c0] = o0;
    *(ushort4*)&hr[c1] = o1;
}

// ---------------------------------------------------------------------------
// Dilated attention over head-major bf16 q/k/v slabs (R6 design, proven).
// ---------------------------------------------------------------------------
__global__ __launch_bounds__(256) void attn_kernel(
    const unsigned short* __restrict__ qh, const unsigned short* __restrict__ kh,
    const unsigned short* __restrict__ vh, unsigned short* __restrict__ o, int dil)
{
    const int blk  = blockIdx.x;
    const int tile = blk & (TSEQ / 16 - 1);   // 128 query tiles
    const int bh   = blk >> 7;
    const int b    = bh >> 3, hh = bh & 7;
    const int t0   = tile * 16;
    const int wave = threadIdx.x >> 6, lane = threadIdx.x & 63;
    const int tq   = wave * 4 + (lane >> 4);  // query 0..15
    const int s    = lane & 15;               // key slot 0..15
    const int t    = t0 + tq;
    const size_t slab = ((size_t)hh * MROWS + (size_t)b * TSEQ) * HD;

    __shared__ float p_lds[16][17];

    // ---- phase 1: scores + softmax ----
    int row = t - s * dil;
    const bool valid = (row >= 0);
    row = max(row, 0);
    const u16x8* kr = (const u16x8*)(kh + slab + (size_t)row * HD);
    const u16x8* qr = (const u16x8*)(qh + slab + (size_t)t * HD);
    float dot = 0.0f;
#pragma unroll
    for (int j = 0; j < 8; j++) {
        const u16x8 kk = kr[j];
        const u16x8 qq = qr[j];
#pragma unroll
        for (int e = 0; e < 8; e++) dot += b2f(qq[e]) * b2f(kk[e]);
    }
    const float sc = valid ? dot * 0.125f : -1e30f;
    float m = sc;
#pragma unroll
    for (int off = 1; off < 16; off <<= 1) m = fmaxf(m, __shfl_xor(m, off, 64));
    const float p = expf(sc - m);
    float l = p;
#pragma unroll
    for (int off = 1; off < 16; off <<= 1) l += __shfl_xor(l, off, 64);
    p_lds[tq][s] = p / l;
    __syncthreads();

    // ---- phase 2: o = sum_s p * v (lane = dim) ----
#pragma unroll
    for (int qi = 0; qi < 4; qi++) {
        const int qq = qi * 4 + wave;
        const int tt = t0 + qq;
        float acc = 0.0f;
#pragma unroll
        for (int ss = 0; ss < KATT; ss++) {
            int vr = tt - ss * dil;
            const float pw = p_lds[qq][ss];   // exactly 0 for masked slots
            vr = max(vr, 0);
            acc += pw * b2f(vh[slab + (size_t)vr * HD + lane]);
        }
        o[(size_t)(b * TSEQ + tt) * DM + (size_t)hh * HD + lane] = f2b(acc);
    }
}

// ---------------------------------------------------------------------------
// GEMM: C[M,N] = A_bf16[M,K] * Bt_bf16[N,K]^T over K-slice z. BK=64.
// Block = 256 threads (4 waves, 2x2), block tile 128x64, wave tile 64x32:
//   per BK=64 step/wave: 16 MFMA : 12 ds_read_b128, HALF the barriers of BK=32.
// Staging: 64 B contiguous global per thread -> LDS stride 72 shorts (16B-
// aligned rows; frag-read bank starts uniform over groups, same as stride 40).
// Occupancy first (R3/R4/R5 lesson): every launch >= 16 waves/CU; LDS
// 27.6 KB/block -> 5 blocks/CU cap, grids give 4/CU.
//   EPI 0: outp[z*zstride + idx] = bf16(C)   (proj/w2 partials, bf16)
//   EPI 2: outb = bf16(gelu(C + bias))       (w1, exact gelu)
//   EPI 3: split qkv -> head-major bf16 q/k/v slabs
// ---------------------------------------------------------------------------
template<int EPI>
__global__ __launch_bounds__(256) void gemm_kernel(
    const unsigned short* __restrict__ A,   // M x K
    const unsigned short* __restrict__ Bt,  // N x K
    const float* __restrict__ bias,         // N (EPI 2 only)
    unsigned short* __restrict__ outp,      // bf16 partials (EPI 0)
    unsigned short* __restrict__ outb,      // bf16 out (EPI 2)
    unsigned short* __restrict__ outq,      // EPI 3
    unsigned short* __restrict__ outk,      // EPI 3
    unsigned short* __restrict__ outv,      // EPI 3
    int N, int K, int Kslice, size_t zstride)
{
    const int tid  = threadIdx.x;
    const int wave = tid >> 6, lane = tid & 63;
    const int bm = blockIdx.y * 128;
    const int bn = blockIdx.x * 64;
    const int wm = (wave >> 1) * 64;          // wave rows: 64
    const int wn = (wave & 1) * 32;           // wave cols: 32
    const int ml = lane & 15, quad = lane >> 4;
    const int kbeg = blockIdx.z * Kslice;

    __shared__ unsigned short As[128 * 72];   // 18432 B
    __shared__ unsigned short Bs[64 * 72];    //  9216 B

    f32x4 acc[4][2] = {};

    // A staging: thread -> row ar=tid>>1, 64 B chunk ak=(tid&1)*32 (4 uint4)
    const int ar = tid >> 1, ak = (tid & 1) * 32;
    // B staging: thread -> row br=tid>>2, 32 B chunk bk=(tid&3)*16 (2 uint4)
    const int br = tid >> 2, bk = (tid & 3) * 16;
    const unsigned short* Aa = A  + (size_t)(bm + ar) * K + kbeg + ak;
    const unsigned short* Bb = Bt + (size_t)(bn + br) * K + kbeg + bk;

    for (int k0 = 0; k0 < Kslice; k0 += 64) {
        uint4 a[4], b[2];
#pragma unroll
        for (int j = 0; j < 4; j++) a[j] = *(const uint4*)(Aa + k0 + 8 * j);
#pragma unroll
        for (int j = 0; j < 2; j++) b[j] = *(const uint4*)(Bb + k0 + 8 * j);
        __syncthreads();                       // previous tile consumed
#pragma unroll
        for (int j = 0; j < 4; j++) *(uint4*)&As[ar * 72 + ak + 8 * j] = a[j];
#pragma unroll
        for (int j = 0; j < 2; j++) *(uint4*)&Bs[br * 72 + bk + 8 * j] = b[j];
        __syncthreads();                       // staged tile visible

#pragma unroll
        for (int ks = 0; ks < 2; ks++) {
            bf16x8 af[4], bfr[2];
#pragma unroll
            for (int i = 0; i < 4; i++)
                af[i] = *(const bf16x8*)&As[(wm + i * 16 + ml) * 72 + ks * 32 + quad * 8];
#pragma unroll
            for (int j = 0; j < 2; j++)
                bfr[j] = *(const bf16x8*)&Bs[(wn + j * 16 + ml) * 72 + ks * 32 + quad * 8];
#pragma unroll
            for (int i = 0; i < 4; i++)
#pragma unroll
                for (int j = 0; j < 2; j++)
                    acc[i][j] = __builtin_amdgcn_mfma_f32_16x16x32_bf16(
                        af[i], bfr[j], acc[i][j], 0, 0, 0);
        }
    }

    unsigned short* op = outp + (size_t)blockIdx.z * zstride;
#pragma unroll
    for (int i = 0; i < 4; i++)
#pragma unroll
        for (int j = 0; j < 2; j++)
#pragma unroll
            for (int r = 0; r < 4; r++) {
                const int row = bm + wm + i * 16 + quad * 4 + r;  // C/D row=quad*4+reg
                const int col = bn + wn + j * 16 + ml;            // C/D col=lane&15
                const float v = acc[i][j][r];
                if (EPI == 0) {
                    op[(size_t)row * N + col] = f2b(v);
                } else if (EPI == 2) {
                    const float u = v + bias[col];
                    const float g = 0.5f * u * (1.0f + erff(u * 0.70710678118654752f));
                    outb[(size_t)row * N + col] = f2b(g);
                } else {
                    // split qkv: col -> (which, head, dim); head-major bf16
                    const int which = col >> 9;
                    const int hh = (col & 511) >> 6;
                    const int dim = col & 63;
                    unsigned short* dst =
                        which == 0 ? outq : (which == 1 ? outk : outv);
                    dst[((size_t)hh * MROWS + row) * HD + dim] = f2b(v);
                }
            }
}

// ---------------------------------------------------------------------------
// Split-K reduce (bf16 partials) + residual + bias, optionally fused with the
// NEXT LayerNorm:  x' = xin + sum_z part[z] + bias;
//                  if DO_LN: h = LN(x')*lns + lnb (bf16)
// One wave per row. Deterministic f32 sum order; in-place xout==xin safe.
// ---------------------------------------------------------------------------
template<bool DO_LN>
__global__ __launch_bounds__(256) void reduce_kernel(
    const float* __restrict__ xin,
    const unsigned short* __restrict__ part,   // [4][MROWS x DM] bf16
    const float* __restrict__ bias,            // DM
    const float* __restrict__ lns, const float* __restrict__ lnb,
    float* __restrict__ xout, unsigned short* __restrict__ h)
{
    const int wid  = blockIdx.x * 4 + (threadIdx.x >> 6);
    const int lane = threadIdx.x & 63;
    const int c0 = lane * 4, c1 = 256 + lane * 4;
    const size_t ro = (size_t)wid * DM;

    float4 a0 = *(const float4*)&xin[ro + c0];
    float4 a1 = *(const float4*)&xin[ro + c1];
#pragma unroll
    for (int z = 0; z < 4; z++) {
        const unsigned short* p = part + (size_t)z * (MROWS * (size_t)DM) + ro;
        const ushort4 p0 = *(const ushort4*)&p[c0];
        const ushort4 p1 = *(const ushort4*)&p[c1];
        a0.x += b2f(p0.x); a0.y += b2f(p0.y); a0.z += b2f(p0.z); a0.w += b2f(p0.w);
        a1.x += b2f(p1.x); a1.y += b2f(p1.y); a1.z += b2f(p1.z); a1.w += b2f(p1.w);
    }
    a0.x += bias[c0+0]; a0.y += bias[c0+1]; a0.z += bias[c0+2]; a0.w += bias[c0+3];
    a1.x += bias[c1+0]; a1.y += bias[c1+1]; a1.z += bias[c1+2]; a1.w += bias[c1+3];

    *(float4*)&xout[ro + c0] = a0;
    *(float4*)&xout[ro + c1] = a1;

    if (DO_LN) {
        float s = a0.x + a0.y + a0.z + a0.w + a1.x + a1.y + a1.z + a1.w;
        float q = a0.x*a0.x + a0.y*a0.y + a0.z*a0.z + a0.w*a0.w
                + a1.x*a1.x + a1.y*a1.y + a1.z*a1.z + a1.w*a1.w;
#pragma unroll
        for (int off = 32; off; off >>= 1) {
            s += __shfl_xor(s, off, 64);
            q += __shfl_xor(q, off, 64);
        }
        const float mean = s * (1.0f / DM);
        const float var  = q * (1.0f / DM) - mean * mean;
        const float rs   = rsqrtf(var + 1e-5f);
        unsigned short* hr = h + ro;
        ushort4 o0, o1;
        o0.x = f2b((a0.x - mean) * rs * lns[c0+0] + lnb[c0+0]);
        o0.y = f2b((a0.y - mean) * rs * lns[c0+1] + lnb[c0+1]);
        o0.z = f2b((a0.z - mean) * rs * lns[c0+2] + lnb[c0+2]);
        o0.w = f2b((a0.w - mean) * rs * lns[c0+3] + lnb[c0+3]);
        o1.x = f2b((a1.x - mean) * rs * lns[c1+0] + lnb[c1+0]);
        o1.y = f2b((a1.y - mean) * rs * lns[c1+1] + lnb[c1+1]);
        o1.z = f2b((a1.z - mean) * rs * lns[c1+2] + lnb[c1+2]);
        o1.w = f2b((a1.w - mean) * rs * lns[c1+3] + lnb[c1+3]);
        *(ushort4*)&hr[c0] = o0;
        *(ushort4*)&hr[c1] = o1;
    }
}

// ---------------------------------------------------------------------------
extern "C" void kernel_launch(void* const* d_in, const int* in_sizes, int n_in,
                              void* d_out, int out_size, void* d_ws, size_t ws_size,
                              hipStream_t stream)
{
    (void)in_sizes; (void)n_in; (void)out_size; (void)ws_size;
    const float* x_in   = (const float*)d_in[0];
    const float* ln1_s  = (const float*)d_in[1];
    const float* ln1_b  = (const float*)d_in[2];
    const float* qkv_w  = (const float*)d_in[3];
    const float* proj_w = (const float*)d_in[4];
    const float* proj_b = (const float*)d_in[5];
    const float* ln2_s  = (const float*)d_in[6];
    const float* ln2_b  = (const float*)d_in[7];
    const float* w1     = (const float*)d_in[8];
    const float* b1     = (const float*)d_in[9];
    const float* w2     = (const float*)d_in[10];
    const float* b2     = (const float*)d_in[11];

    // Workspace carve-up (bytes)
    char* ws = (char*)d_ws;
    float*          xbuf = (float*)(ws);                        //   0 MB, 8 MB
    unsigned short* qhb  = (unsigned short*)(ws + 8388608);     //   8 MB, 4 MB bf16 [8][4096][64]
    unsigned short* khb  = (unsigned short*)(ws + 12582912);    //  12 MB, 4 MB
    unsigned short* vhb  = (unsigned short*)(ws + 16777216);    //  16 MB, 4 MB
    unsigned short* ubuf = (unsigned short*)(ws + 33554432);    //  32 MB, 16 MB bf16
    unsigned short* hbuf = (unsigned short*)(ws + 50331648);    //  48 MB, 4 MB
    unsigned short* obuf = (unsigned short*)(ws + 54525952);    //  52 MB, 4 MB
    unsigned short* part = (unsigned short*)(ws + 58720256);    //  56 MB, 16 MB bf16 [4][4096x512]
    unsigned short* qkvT = (unsigned short*)(ws + 92274688);    //  88 MB
    unsigned short* projT= (unsigned short*)(ws + 96993280);
    unsigned short* w1T  = (unsigned short*)(ws + 98566144);
    unsigned short* w2T  = (unsigned short*)(ws + 104857600);   // ends 106 MB

    const size_t ZS = (size_t)MROWS * DM;   // partial-slice stride (elements)

    hipMemcpyAsync(xbuf, x_in, (size_t)MROWS * DM * sizeof(float),
                   hipMemcpyDeviceToDevice, stream);

    transpose_w_kernel<<<dim3(1536/32, 512/32, 3),  dim3(32, 8), 0, stream>>>(qkv_w,  qkvT, 512, 1536);
    transpose_w_kernel<<<dim3( 512/32, 512/32, 3),  dim3(32, 8), 0, stream>>>(proj_w, projT, 512, 512);
    transpose_w_kernel<<<dim3(2048/32, 512/32, 3),  dim3(32, 8), 0, stream>>>(w1,     w1T,  512, 2048);
    transpose_w_kernel<<<dim3( 512/32, 2048/32, 3), dim3(32, 8), 0, stream>>>(w2,     w2T, 2048, 512);

    // depth-0 LN1 (later LNs fused into reduce_kernel)
    ln_kernel<<<MROWS / 4, 256, 0, stream>>>(xbuf, ln1_s, ln1_b, hbuf);

    for (int d = 0; d < NDEPTH; d++) {
        const int dil = 1 << d;

        // qkv = h @ qkv_w -> head-major bf16 q/k/v. grid (24,32) = 768 blocks.
        gemm_kernel<3><<<dim3(1536/64, MROWS/128, 1), 256, 0, stream>>>(
            hbuf, qkvT + (size_t)d * 1536 * 512, nullptr, nullptr, nullptr,
            qhb, khb, vhb, 1536, 512, 512, 0);
        // dilated attention -> o (bf16)
        attn_kernel<<<2 * NH * (TSEQ / 16), 256, 0, stream>>>(qhb, khb, vhb, obuf, dil);
        // proj partials (bf16): split-K x4, Kslice 128. grid (8,32,4) = 1024 blocks.
        gemm_kernel<0><<<dim3(512/64, MROWS/128, 4), 256, 0, stream>>>(
            obuf, projT + (size_t)d * 512 * 512, nullptr, part, nullptr,
            nullptr, nullptr, nullptr, 512, 512, 128, ZS);
        // x += sum(part) + proj_b ; h = LN2(x) fused
        reduce_kernel<true><<<MROWS / 4, 256, 0, stream>>>(
            xbuf, part, proj_b + d * DM, ln2_s + d * DM, ln2_b + d * DM,
            xbuf, hbuf);
        // u = gelu(h @ w1 + b1). grid (32,32) = 1024 blocks.
        gemm_kernel<2><<<dim3(2048/64, MROWS/128, 1), 256, 0, stream>>>(
            hbuf, w1T + (size_t)d * 2048 * 512, b1 + d * 2048, nullptr, ubuf,
            nullptr, nullptr, nullptr, 2048, 512, 512, 0);
        // w2 partials (bf16): split-K x4, Kslice 512. grid (8,32,4) = 1024 blocks.
        gemm_kernel<0><<<dim3(512/64, MROWS/128, 4), 256, 0, stream>>>(
            ubuf, w2T + (size_t)d * 512 * 2048, nullptr, part, nullptr,
            nullptr, nullptr, nullptr, 512, 2048, 512, ZS);
        // x += sum(part) + b2 ; fuse next depth's LN1 (or final write to d_out)
        if (d < NDEPTH - 1) {
            reduce_kernel<true><<<MROWS / 4, 256, 0, stream>>>(
                xbuf, part, b2 + d * DM, ln1_s + (d+1) * DM, ln1_b + (d+1) * DM,
                xbuf, hbuf);
        } else {
            reduce_kernel<false><<<MROWS / 4, 256, 0, stream>>>(
                xbuf, part, b2 + d * DM, nullptr, nullptr,
                (float*)d_out, nullptr);
        }
    }
}

// Round 9
// 439.746 us; speedup vs baseline: 1.7960x; 1.7960x over previous
//
#include <hip/hip_runtime.h>
#include <math.h>

// Problem constants (B=2, T=2048, D=512, H=8, hd=64, K=16, DEPTH=3)
#define TSEQ   2048
#define DM     512
#define NH     8
#define HD     64
#define KATT   16
#define NDEPTH 3
#define MROWS  4096   // B*T

typedef __attribute__((ext_vector_type(8))) short bf16x8;
typedef __attribute__((ext_vector_type(8))) unsigned short u16x8;
typedef __attribute__((ext_vector_type(4))) float f32x4;

// f32 -> bf16 (round-to-nearest-even), bit-level
static __device__ __forceinline__ unsigned short f2b(float f) {
    unsigned int u = __float_as_uint(f);
    unsigned int r = (u + 0x7fffu + ((u >> 16) & 1u)) >> 16;
    return (unsigned short)r;
}
// bf16 bits -> f32
static __device__ __forceinline__ float b2f(unsigned short s) {
    return __uint_as_float((unsigned int)s << 16);
}

// ---------------------------------------------------------------------------
// Weight prep: W f32 [K x N] (per depth) -> Wt bf16 [N x K]. grid.z = depth.
// ---------------------------------------------------------------------------
__global__ __launch_bounds__(256) void transpose_w_kernel(
    const float* __restrict__ W, unsigned short* __restrict__ Wt, int Kd, int Nd)
{
    __shared__ float tile[32][33];
    const int n0 = blockIdx.x * 32, k0 = blockIdx.y * 32;
    const size_t off = (size_t)blockIdx.z * Kd * Nd;
    const float* Wd = W + off;
    unsigned short* Wtd = Wt + off;
    const int tx = threadIdx.x, ty = threadIdx.y;
#pragma unroll
    for (int r = 0; r < 32; r += 8)
        tile[ty + r][tx] = Wd[(size_t)(k0 + ty + r) * Nd + (n0 + tx)];
    __syncthreads();
#pragma unroll
    for (int r = 0; r < 32; r += 8)
        Wtd[(size_t)(n0 + ty + r) * Kd + (k0 + tx)] = f2b(tile[tx][ty + r]);
}

// ---------------------------------------------------------------------------
// LayerNorm: x f32 [4096 x 512] -> h bf16 [4096 x 512]. One wave per row.
// (only used for depth-0 LN1; later LNs are fused into reduce_kernel)
// ---------------------------------------------------------------------------
__global__ __launch_bounds__(256) void ln_kernel(
    const float* __restrict__ x, const float* __restrict__ sc,
    const float* __restrict__ bi, unsigned short* __restrict__ h)
{
    const int wid  = blockIdx.x * 4 + (threadIdx.x >> 6);
    const int lane = threadIdx.x & 63;
    const float* xr = x + (size_t)wid * DM;
    const float4 v0 = *(const float4*)&xr[lane * 4];
    const float4 v1 = *(const float4*)&xr[256 + lane * 4];
    float s = v0.x + v0.y + v0.z + v0.w + v1.x + v1.y + v1.z + v1.w;
    float q = v0.x*v0.x + v0.y*v0.y + v0.z*v0.z + v0.w*v0.w
            + v1.x*v1.x + v1.y*v1.y + v1.z*v1.z + v1.w*v1.w;
#pragma unroll
    for (int off = 32; off; off >>= 1) {
        s += __shfl_xor(s, off, 64);
        q += __shfl_xor(q, off, 64);
    }
    const float mean = s * (1.0f / DM);
    const float var  = q * (1.0f / DM) - mean * mean;
    const float rs   = rsqrtf(var + 1e-5f);
    unsigned short* hr = h + (size_t)wid * DM;
    const int c0 = lane * 4, c1 = 256 + lane * 4;
    ushort4 o0, o1;
    o0.x = f2b((v0.x - mean) * rs * sc[c0+0] + bi[c0+0]);
    o0.y = f2b((v0.y - mean) * rs * sc[c0+1] + bi[c0+1]);
    o0.z = f2b((v0.z - mean) * rs * sc[c0+2] + bi[c0+2]);
    o0.w = f2b((v0.w - mean) * rs * sc[c0+3] + bi[c0+3]);
    o1.x = f2b((v1.x - mean) * rs * sc[c1+0] + bi[c1+0]);
    o1.y = f2b((v1.y - mean) * rs * sc[c1+1] + bi[c1+1]);
    o1.z = f2b((v1.z - mean) * rs * sc[c1+2] + bi[c1+2]);
    o1.w = f2b((v1.w - mean) * rs * sc[c1+3] + bi[c1+3]);
    *(ushort4*)&hr[c0] = o0;
    *(ushort4*)&hr[c1] = o1;
}

// ---------------------------------------------------------------------------
// Dilated attention over head-major bf16 q/k/v slabs (R6 design, proven).
// ---------------------------------------------------------------------------
__global__ __launch_bounds__(256) void attn_kernel(
    const unsigned short* __restrict__ qh, const unsigned short* __restrict__ kh,
    const unsigned short* __restrict__ vh, unsigned short* __restrict__ o, int dil)
{
    const int blk  = blockIdx.x;
    const int tile = blk & (TSEQ / 16 - 1);   // 128 query tiles
    const int bh   = blk >> 7;
    const int b    = bh >> 3, hh = bh & 7;
    const int t0   = tile * 16;
    const int wave = threadIdx.x >> 6, lane = threadIdx.x & 63;
    const int tq   = wave * 4 + (lane >> 4);  // query 0..15
    const int s    = lane & 15;               // key slot 0..15
    const int t    = t0 + tq;
    const size_t slab = ((size_t)hh * MROWS + (size_t)b * TSEQ) * HD;

    __shared__ float p_lds[16][17];

    // ---- phase 1: scores + softmax ----
    int row = t - s * dil;
    const bool valid = (row >= 0);
    row = max(row, 0);
    const u16x8* kr = (const u16x8*)(kh + slab + (size_t)row * HD);
    const u16x8* qr = (const u16x8*)(qh + slab + (size_t)t * HD);
    float dot = 0.0f;
#pragma unroll
    for (int j = 0; j < 8; j++) {
        const u16x8 kk = kr[j];
        const u16x8 qq = qr[j];
#pragma unroll
        for (int e = 0; e < 8; e++) dot += b2f(qq[e]) * b2f(kk[e]);
    }
    const float sc = valid ? dot * 0.125f : -1e30f;
    float m = sc;
#pragma unroll
    for (int off = 1; off < 16; off <<= 1) m = fmaxf(m, __shfl_xor(m, off, 64));
    const float p = expf(sc - m);
    float l = p;
#pragma unroll
    for (int off = 1; off < 16; off <<= 1) l += __shfl_xor(l, off, 64);
    p_lds[tq][s] = p / l;
    __syncthreads();

    // ---- phase 2: o = sum_s p * v (lane = dim) ----
#pragma unroll
    for (int qi = 0; qi < 4; qi++) {
        const int qq = qi * 4 + wave;
        const int tt = t0 + qq;
        float acc = 0.0f;
#pragma unroll
        for (int ss = 0; ss < KATT; ss++) {
            int vr = tt - ss * dil;
            const float pw = p_lds[qq][ss];   // exactly 0 for masked slots
            vr = max(vr, 0);
            acc += pw * b2f(vh[slab + (size_t)vr * HD + lane]);
        }
        o[(size_t)(b * TSEQ + tt) * DM + (size_t)hh * HD + lane] = f2b(acc);
    }
}

// ---------------------------------------------------------------------------
// GEMM (R6-proven structure, VERBATIM k-loop): C = A_bf16[M,K] * Bt[N,K]^T
// over K-slice z. BK=32, block 128x64 (4 waves 2x2, wave 64x32):
//   per BK=32 step/wave: 8 MFMA : 6 ds_read_b128; VGPR 72, no spill;
//   LDS stride 40 shorts (80 B = 20 banks -> full bank spread, 0 conflicts).
// R7 lesson (measured): BK=64 -> VGPR spill to scratch (165 MB HBM writes)
// + stride-72 bank conflicts. Do not raise BK without checking VGPR count.
//   EPI 0: outp[z*zstride + idx] = bf16(C)   (proj/w2 partials, bf16)
//   EPI 2: outb = bf16(gelu(C + bias))       (w1, exact gelu)
//   EPI 3: split qkv -> head-major bf16 q/k/v slabs
// ---------------------------------------------------------------------------
template<int EPI>
__global__ __launch_bounds__(256) void gemm_kernel(
    const unsigned short* __restrict__ A,   // M x K
    const unsigned short* __restrict__ Bt,  // N x K
    const float* __restrict__ bias,         // N (EPI 2 only)
    unsigned short* __restrict__ outp,      // bf16 partials (EPI 0)
    unsigned short* __restrict__ outb,      // bf16 out (EPI 2)
    unsigned short* __restrict__ outq,      // EPI 3
    unsigned short* __restrict__ outk,      // EPI 3
    unsigned short* __restrict__ outv,      // EPI 3
    int N, int K, int Kslice, size_t zstride)
{
    const int tid  = threadIdx.x;
    const int wave = tid >> 6, lane = tid & 63;
    const int bm = blockIdx.y * 128;
    const int bn = blockIdx.x * 64;
    const int wm = (wave >> 1) * 64;          // wave rows: 64
    const int wn = (wave & 1) * 32;           // wave cols: 32
    const int ml = lane & 15, quad = lane >> 4;
    const int kbeg = blockIdx.z * Kslice;

    __shared__ unsigned short As[128 * 40];   // 10240 B
    __shared__ unsigned short Bs[64 * 40];    //  5120 B

    f32x4 acc[4][2] = {};

    const int ar = tid >> 1, ac = (tid & 1) * 16;   // A: 2 uint4 / thread
    const int br = tid >> 2, bc = (tid & 3) * 8;    // B: 1 uint4 / thread
    const unsigned short* Aa = A  + (size_t)(bm + ar) * K + kbeg + ac;
    const unsigned short* Bb = Bt + (size_t)(bn + br) * K + kbeg + bc;

    for (int k0 = 0; k0 < Kslice; k0 += 32) {
        const uint4 a0 = *(const uint4*)(Aa + k0);
        const uint4 a1 = *(const uint4*)(Aa + k0 + 8);
        const uint4 b0 = *(const uint4*)(Bb + k0);
        __syncthreads();                       // previous tile consumed
        *(uint4*)&As[ar * 40 + ac]     = a0;
        *(uint4*)&As[ar * 40 + ac + 8] = a1;
        *(uint4*)&Bs[br * 40 + bc]     = b0;
        __syncthreads();                       // staged tile visible

        bf16x8 af[4], bfr[2];
#pragma unroll
        for (int i = 0; i < 4; i++)
            af[i] = *(const bf16x8*)&As[(wm + i * 16 + ml) * 40 + quad * 8];
#pragma unroll
        for (int j = 0; j < 2; j++)
            bfr[j] = *(const bf16x8*)&Bs[(wn + j * 16 + ml) * 40 + quad * 8];
#pragma unroll
        for (int i = 0; i < 4; i++)
#pragma unroll
            for (int j = 0; j < 2; j++)
                acc[i][j] = __builtin_amdgcn_mfma_f32_16x16x32_bf16(
                    af[i], bfr[j], acc[i][j], 0, 0, 0);
    }

    unsigned short* op = outp + (size_t)blockIdx.z * zstride;
#pragma unroll
    for (int i = 0; i < 4; i++)
#pragma unroll
        for (int j = 0; j < 2; j++)
#pragma unroll
            for (int r = 0; r < 4; r++) {
                const int row = bm + wm + i * 16 + quad * 4 + r;  // C/D row=quad*4+reg
                const int col = bn + wn + j * 16 + ml;            // C/D col=lane&15
                const float v = acc[i][j][r];
                if (EPI == 0) {
                    op[(size_t)row * N + col] = f2b(v);
                } else if (EPI == 2) {
                    const float u = v + bias[col];
                    const float g = 0.5f * u * (1.0f + erff(u * 0.70710678118654752f));
                    outb[(size_t)row * N + col] = f2b(g);
                } else {
                    // split qkv: col -> (which, head, dim); head-major bf16
                    const int which = col >> 9;
                    const int hh = (col & 511) >> 6;
                    const int dim = col & 63;
                    unsigned short* dst =
                        which == 0 ? outq : (which == 1 ? outk : outv);
                    dst[((size_t)hh * MROWS + row) * HD + dim] = f2b(v);
                }
            }
}

// ---------------------------------------------------------------------------
// Split-K reduce (bf16 partials) + residual + bias, optionally fused with the
// NEXT LayerNorm:  x' = xin + sum_z part[z] + bias;
//                  if DO_LN: h = LN(x')*lns + lnb (bf16)
// One wave per row. Deterministic f32 sum order; in-place xout==xin safe.
// ---------------------------------------------------------------------------
template<bool DO_LN>
__global__ __launch_bounds__(256) void reduce_kernel(
    const float* __restrict__ xin,
    const unsigned short* __restrict__ part,   // [4][MROWS x DM] bf16
    const float* __restrict__ bias,            // DM
    const float* __restrict__ lns, const float* __restrict__ lnb,
    float* __restrict__ xout, unsigned short* __restrict__ h)
{
    const int wid  = blockIdx.x * 4 + (threadIdx.x >> 6);
    const int lane = threadIdx.x & 63;
    const int c0 = lane * 4, c1 = 256 + lane * 4;
    const size_t ro = (size_t)wid * DM;

    float4 a0 = *(const float4*)&xin[ro + c0];
    float4 a1 = *(const float4*)&xin[ro + c1];
#pragma unroll
    for (int z = 0; z < 4; z++) {
        const unsigned short* p = part + (size_t)z * (MROWS * (size_t)DM) + ro;
        const ushort4 p0 = *(const ushort4*)&p[c0];
        const ushort4 p1 = *(const ushort4*)&p[c1];
        a0.x += b2f(p0.x); a0.y += b2f(p0.y); a0.z += b2f(p0.z); a0.w += b2f(p0.w);
        a1.x += b2f(p1.x); a1.y += b2f(p1.y); a1.z += b2f(p1.z); a1.w += b2f(p1.w);
    }
    a0.x += bias[c0+0]; a0.y += bias[c0+1]; a0.z += bias[c0+2]; a0.w += bias[c0+3];
    a1.x += bias[c1+0]; a1.y += bias[c1+1]; a1.z += bias[c1+2]; a1.w += bias[c1+3];

    *(float4*)&xout[ro + c0] = a0;
    *(float4*)&xout[ro + c1] = a1;

    if (DO_LN) {
        float s = a0.x + a0.y + a0.z + a0.w + a1.x + a1.y + a1.z + a1.w;
        float q = a0.x*a0.x + a0.y*a0.y + a0.z*a0.z + a0.w*a0.w
                + a1.x*a1.x + a1.y*a1.y + a1.z*a1.z + a1.w*a1.w;
#pragma unroll
        for (int off = 32; off; off >>= 1) {
            s += __shfl_xor(s, off, 64);
            q += __shfl_xor(q, off, 64);
        }
        const float mean = s * (1.0f / DM);
        const float var  = q * (1.0f / DM) - mean * mean;
        const float rs   = rsqrtf(var + 1e-5f);
        unsigned short* hr = h + ro;
        ushort4 o0, o1;
        o0.x = f2b((a0.x - mean) * rs * lns[c0+0] + lnb[c0+0]);
        o0.y = f2b((a0.y - mean) * rs * lns[c0+1] + lnb[c0+1]);
        o0.z = f2b((a0.z - mean) * rs * lns[c0+2] + lnb[c0+2]);
        o0.w = f2b((a0.w - mean) * rs * lns[c0+3] + lnb[c0+3]);
        o1.x = f2b((a1.x - mean) * rs * lns[c1+0] + lnb[c1+0]);
        o1.y = f2b((a1.y - mean) * rs * lns[c1+1] + lnb[c1+1]);
        o1.z = f2b((a1.z - mean) * rs * lns[c1+2] + lnb[c1+2]);
        o1.w = f2b((a1.w - mean) * rs * lns[c1+3] + lnb[c1+3]);
        *(ushort4*)&hr[c0] = o0;
        *(ushort4*)&hr[c1] = o1;
    }
}

// ---------------------------------------------------------------------------
extern "C" void kernel_launch(void* const* d_in, const int* in_sizes, int n_in,
                              void* d_out, int out_size, void* d_ws, size_t ws_size,
                              hipStream_t stream)
{
    (void)in_sizes; (void)n_in; (void)out_size; (void)ws_size;
    const float* x_in   = (const float*)d_in[0];
    const float* ln1_s  = (const float*)d_in[1];
    const float* ln1_b  = (const float*)d_in[2];
    const float* qkv_w  = (const float*)d_in[3];
    const float* proj_w = (const float*)d_in[4];
    const float* proj_b = (const float*)d_in[5];
    const float* ln2_s  = (const float*)d_in[6];
    const float* ln2_b  = (const float*)d_in[7];
    const float* w1     = (const float*)d_in[8];
    const float* b1     = (const float*)d_in[9];
    const float* w2     = (const float*)d_in[10];
    const float* b2     = (const float*)d_in[11];

    // Workspace carve-up (bytes)
    char* ws = (char*)d_ws;
    float*          xbuf = (float*)(ws);                        //   0 MB, 8 MB
    unsigned short* qhb  = (unsigned short*)(ws + 8388608);     //   8 MB, 4 MB bf16 [8][4096][64]
    unsigned short* khb  = (unsigned short*)(ws + 12582912);    //  12 MB, 4 MB
    unsigned short* vhb  = (unsigned short*)(ws + 16777216);    //  16 MB, 4 MB
    unsigned short* ubuf = (unsigned short*)(ws + 33554432);    //  32 MB, 16 MB bf16
    unsigned short* hbuf = (unsigned short*)(ws + 50331648);    //  48 MB, 4 MB
    unsigned short* obuf = (unsigned short*)(ws + 54525952);    //  52 MB, 4 MB
    unsigned short* part = (unsigned short*)(ws + 58720256);    //  56 MB, 16 MB bf16 [4][4096x512]
    unsigned short* qkvT = (unsigned short*)(ws + 92274688);    //  88 MB
    unsigned short* projT= (unsigned short*)(ws + 96993280);
    unsigned short* w1T  = (unsigned short*)(ws + 98566144);
    unsigned short* w2T  = (unsigned short*)(ws + 104857600);   // ends 106 MB

    const size_t ZS = (size_t)MROWS * DM;   // partial-slice stride (elements)

    hipMemcpyAsync(xbuf, x_in, (size_t)MROWS * DM * sizeof(float),
                   hipMemcpyDeviceToDevice, stream);

    transpose_w_kernel<<<dim3(1536/32, 512/32, 3),  dim3(32, 8), 0, stream>>>(qkv_w,  qkvT, 512, 1536);
    transpose_w_kernel<<<dim3( 512/32, 512/32, 3),  dim3(32, 8), 0, stream>>>(proj_w, projT, 512, 512);
    transpose_w_kernel<<<dim3(2048/32, 512/32, 3),  dim3(32, 8), 0, stream>>>(w1,     w1T,  512, 2048);
    transpose_w_kernel<<<dim3( 512/32, 2048/32, 3), dim3(32, 8), 0, stream>>>(w2,     w2T, 2048, 512);

    // depth-0 LN1 (later LNs fused into reduce_kernel)
    ln_kernel<<<MROWS / 4, 256, 0, stream>>>(xbuf, ln1_s, ln1_b, hbuf);

    for (int d = 0; d < NDEPTH; d++) {
        const int dil = 1 << d;

        // qkv = h @ qkv_w -> head-major bf16 q/k/v. grid (24,32) = 768 blocks.
        gemm_kernel<3><<<dim3(1536/64, MROWS/128, 1), 256, 0, stream>>>(
            hbuf, qkvT + (size_t)d * 1536 * 512, nullptr, nullptr, nullptr,
            qhb, khb, vhb, 1536, 512, 512, 0);
        // dilated attention -> o (bf16)
        attn_kernel<<<2 * NH * (TSEQ / 16), 256, 0, stream>>>(qhb, khb, vhb, obuf, dil);
        // proj partials (bf16): split-K x4, Kslice 128. grid (8,32,4) = 1024 blocks.
        gemm_kernel<0><<<dim3(512/64, MROWS/128, 4), 256, 0, stream>>>(
            obuf, projT + (size_t)d * 512 * 512, nullptr, part, nullptr,
            nullptr, nullptr, nullptr, 512, 512, 128, ZS);
        // x += sum(part) + proj_b ; h = LN2(x) fused
        reduce_kernel<true><<<MROWS / 4, 256, 0, stream>>>(
            xbuf, part, proj_b + d * DM, ln2_s + d * DM, ln2_b + d * DM,
            xbuf, hbuf);
        // u = gelu(h @ w1 + b1). grid (32,32) = 1024 blocks.
        gemm_kernel<2><<<dim3(2048/64, MROWS/128, 1), 256, 0, stream>>>(
            hbuf, w1T + (size_t)d * 2048 * 512, b1 + d * 2048, nullptr, ubuf,
            nullptr, nullptr, nullptr, 2048, 512, 512, 0);
        // w2 partials (bf16): split-K x4, Kslice 512. grid (8,32,4) = 1024 blocks.
        gemm_kernel<0><<<dim3(512/64, MROWS/128, 4), 256, 0, stream>>>(
            ubuf, w2T + (size_t)d * 512 * 2048, nullptr, part, nullptr,
            nullptr, nullptr, nullptr, 512, 2048, 512, ZS);
        // x += sum(part) + b2 ; fuse next depth's LN1 (or final write to d_out)
        if (d < NDEPTH - 1) {
            reduce_kernel<true><<<MROWS / 4, 256, 0, stream>>>(
                xbuf, part, b2 + d * DM, ln1_s + (d+1) * DM, ln1_b + (d+1) * DM,
                xbuf, hbuf);
        } else {
            reduce_kernel<false><<<MROWS / 4, 256, 0, stream>>>(
                xbuf, part, b2 + d * DM, nullptr, nullptr,
                (float*)d_out, nullptr);
        }
    }
}

// Round 10
// 428.207 us; speedup vs baseline: 1.8444x; 1.0269x over previous
//
#include <hip/hip_runtime.h>
#include <math.h>

// Problem constants (B=2, T=2048, D=512, H=8, hd=64, K=16, DEPTH=3)
#define TSEQ   2048
#define DM     512
#define NH     8
#define HD     64
#define KATT   16
#define NDEPTH 3
#define MROWS  4096   // B*T

typedef __attribute__((ext_vector_type(8))) short bf16x8;
typedef __attribute__((ext_vector_type(8))) unsigned short u16x8;
typedef __attribute__((ext_vector_type(4))) float f32x4;

// f32 -> bf16 (round-to-nearest-even), bit-level
static __device__ __forceinline__ unsigned short f2b(float f) {
    unsigned int u = __float_as_uint(f);
    unsigned int r = (u + 0x7fffu + ((u >> 16) & 1u)) >> 16;
    return (unsigned short)r;
}
// bf16 bits -> f32
static __device__ __forceinline__ float b2f(unsigned short s) {
    return __uint_as_float((unsigned int)s << 16);
}

// ---------------------------------------------------------------------------
// Weight prep: W f32 [K x N] (per depth) -> Wt bf16 [N x K]. grid.z = depth.
// ---------------------------------------------------------------------------
__global__ __launch_bounds__(256) void transpose_w_kernel(
    const float* __restrict__ W, unsigned short* __restrict__ Wt, int Kd, int Nd)
{
    __shared__ float tile[32][33];
    const int n0 = blockIdx.x * 32, k0 = blockIdx.y * 32;
    const size_t off = (size_t)blockIdx.z * Kd * Nd;
    const float* Wd = W + off;
    unsigned short* Wtd = Wt + off;
    const int tx = threadIdx.x, ty = threadIdx.y;
#pragma unroll
    for (int r = 0; r < 32; r += 8)
        tile[ty + r][tx] = Wd[(size_t)(k0 + ty + r) * Nd + (n0 + tx)];
    __syncthreads();
#pragma unroll
    for (int r = 0; r < 32; r += 8)
        Wtd[(size_t)(n0 + ty + r) * Kd + (k0 + tx)] = f2b(tile[tx][ty + r]);
}

// ---------------------------------------------------------------------------
// LayerNorm: x f32 [4096 x 512] -> h bf16 [4096 x 512]. One wave per row.
// (only used for depth-0 LN1; later LNs are fused into reduce_kernel)
// ---------------------------------------------------------------------------
__global__ __launch_bounds__(256) void ln_kernel(
    const float* __restrict__ x, const float* __restrict__ sc,
    const float* __restrict__ bi, unsigned short* __restrict__ h)
{
    const int wid  = blockIdx.x * 4 + (threadIdx.x >> 6);
    const int lane = threadIdx.x & 63;
    const float* xr = x + (size_t)wid * DM;
    const float4 v0 = *(const float4*)&xr[lane * 4];
    const float4 v1 = *(const float4*)&xr[256 + lane * 4];
    float s = v0.x + v0.y + v0.z + v0.w + v1.x + v1.y + v1.z + v1.w;
    float q = v0.x*v0.x + v0.y*v0.y + v0.z*v0.z + v0.w*v0.w
            + v1.x*v1.x + v1.y*v1.y + v1.z*v1.z + v1.w*v1.w;
#pragma unroll
    for (int off = 32; off; off >>= 1) {
        s += __shfl_xor(s, off, 64);
        q += __shfl_xor(q, off, 64);
    }
    const float mean = s * (1.0f / DM);
    const float var  = q * (1.0f / DM) - mean * mean;
    const float rs   = rsqrtf(var + 1e-5f);
    unsigned short* hr = h + (size_t)wid * DM;
    const int c0 = lane * 4, c1 = 256 + lane * 4;
    ushort4 o0, o1;
    o0.x = f2b((v0.x - mean) * rs * sc[c0+0] + bi[c0+0]);
    o0.y = f2b((v0.y - mean) * rs * sc[c0+1] + bi[c0+1]);
    o0.z = f2b((v0.z - mean) * rs * sc[c0+2] + bi[c0+2]);
    o0.w = f2b((v0.w - mean) * rs * sc[c0+3] + bi[c0+3]);
    o1.x = f2b((v1.x - mean) * rs * sc[c1+0] + bi[c1+0]);
    o1.y = f2b((v1.y - mean) * rs * sc[c1+1] + bi[c1+1]);
    o1.z = f2b((v1.z - mean) * rs * sc[c1+2] + bi[c1+2]);
    o1.w = f2b((v1.w - mean) * rs * sc[c1+3] + bi[c1+3]);
    *(ushort4*)&hr[c0] = o0;
    *(ushort4*)&hr[c1] = o1;
}

// ---------------------------------------------------------------------------
// Dilated attention over head-major bf16 q/k/v slabs (R6 design, proven).
// ---------------------------------------------------------------------------
__global__ __launch_bounds__(256) void attn_kernel(
    const unsigned short* __restrict__ qh, const unsigned short* __restrict__ kh,
    const unsigned short* __restrict__ vh, unsigned short* __restrict__ o, int dil)
{
    const int blk  = blockIdx.x;
    const int tile = blk & (TSEQ / 16 - 1);   // 128 query tiles
    const int bh   = blk >> 7;
    const int b    = bh >> 3, hh = bh & 7;
    const int t0   = tile * 16;
    const int wave = threadIdx.x >> 6, lane = threadIdx.x & 63;
    const int tq   = wave * 4 + (lane >> 4);  // query 0..15
    const int s    = lane & 15;               // key slot 0..15
    const int t    = t0 + tq;
    const size_t slab = ((size_t)hh * MROWS + (size_t)b * TSEQ) * HD;

    __shared__ float p_lds[16][17];

    // ---- phase 1: scores + softmax ----
    int row = t - s * dil;
    const bool valid = (row >= 0);
    row = max(row, 0);
    const u16x8* kr = (const u16x8*)(kh + slab + (size_t)row * HD);
    const u16x8* qr = (const u16x8*)(qh + slab + (size_t)t * HD);
    float dot = 0.0f;
#pragma unroll
    for (int j = 0; j < 8; j++) {
        const u16x8 kk = kr[j];
        const u16x8 qq = qr[j];
#pragma unroll
        for (int e = 0; e < 8; e++) dot += b2f(qq[e]) * b2f(kk[e]);
    }
    const float sc = valid ? dot * 0.125f : -1e30f;
    float m = sc;
#pragma unroll
    for (int off = 1; off < 16; off <<= 1) m = fmaxf(m, __shfl_xor(m, off, 64));
    const float p = expf(sc - m);
    float l = p;
#pragma unroll
    for (int off = 1; off < 16; off <<= 1) l += __shfl_xor(l, off, 64);
    p_lds[tq][s] = p / l;
    __syncthreads();

    // ---- phase 2: o = sum_s p * v (lane = dim) ----
#pragma unroll
    for (int qi = 0; qi < 4; qi++) {
        const int qq = qi * 4 + wave;
        const int tt = t0 + qq;
        float acc = 0.0f;
#pragma unroll
        for (int ss = 0; ss < KATT; ss++) {
            int vr = tt - ss * dil;
            const float pw = p_lds[qq][ss];   // exactly 0 for masked slots
            vr = max(vr, 0);
            acc += pw * b2f(vh[slab + (size_t)vr * HD + lane]);
        }
        o[(size_t)(b * TSEQ + tt) * DM + (size_t)hh * HD + lane] = f2b(acc);
    }
}

// ---------------------------------------------------------------------------
// GEMM (R8 structure + LDS double-buffer & prefetch): C = A_bf16[M,K] *
// Bt[N,K]^T over K-slice z. BK=32, block 128x64 (4 waves 2x2, wave 64x32):
//   per k-step/wave: 8 MFMA : 6 ds_read_b128 : 3 ds_write_b128, ONE barrier
//   (was two). Next tile's global loads issue at step top and their latency
//   overlaps frag reads + MFMA via the load->ds_write dependency chain.
// LDS stride 40 shorts (80 B -> full bank spread, 0 conflicts). 2x15 KB bufs.
// VGPR audit (R7 lesson): acc 32 + frags 24 + stage 12 + addr ~15 ~= 90,
// same 4-waves/SIMD bin as R8's 72 -> no occupancy change, no spill.
//   EPI 0: outp[z*zstride + idx] = bf16(C)   (proj/w2 partials, bf16)
//   EPI 2: outb = bf16(gelu(C + bias))       (w1, exact gelu)
//   EPI 3: split qkv -> head-major bf16 q/k/v slabs
// ---------------------------------------------------------------------------
template<int EPI>
__global__ __launch_bounds__(256) void gemm_kernel(
    const unsigned short* __restrict__ A,   // M x K
    const unsigned short* __restrict__ Bt,  // N x K
    const float* __restrict__ bias,         // N (EPI 2 only)
    unsigned short* __restrict__ outp,      // bf16 partials (EPI 0)
    unsigned short* __restrict__ outb,      // bf16 out (EPI 2)
    unsigned short* __restrict__ outq,      // EPI 3
    unsigned short* __restrict__ outk,      // EPI 3
    unsigned short* __restrict__ outv,      // EPI 3
    int N, int K, int Kslice, size_t zstride)
{
    const int tid  = threadIdx.x;
    const int wave = tid >> 6, lane = tid & 63;
    const int bm = blockIdx.y * 128;
    const int bn = blockIdx.x * 64;
    const int wm = (wave >> 1) * 64;          // wave rows: 64
    const int wn = (wave & 1) * 32;           // wave cols: 32
    const int ml = lane & 15, quad = lane >> 4;
    const int kbeg = blockIdx.z * Kslice;

    __shared__ unsigned short As[2][128 * 40];   // 2 x 10240 B
    __shared__ unsigned short Bs[2][64 * 40];    // 2 x  5120 B

    f32x4 acc[4][2] = {};

    const int ar = tid >> 1, ac = (tid & 1) * 16;   // A: 2 uint4 / thread
    const int br = tid >> 2, bc = (tid & 3) * 8;    // B: 1 uint4 / thread
    const unsigned short* Aa = A  + (size_t)(bm + ar) * K + kbeg + ac;
    const unsigned short* Bb = Bt + (size_t)(bn + br) * K + kbeg + bc;

    // preload tile 0 into buffer 0
    uint4 a0 = *(const uint4*)(Aa);
    uint4 a1 = *(const uint4*)(Aa + 8);
    uint4 b0 = *(const uint4*)(Bb);
    *(uint4*)&As[0][ar * 40 + ac]     = a0;
    *(uint4*)&As[0][ar * 40 + ac + 8] = a1;
    *(uint4*)&Bs[0][br * 40 + bc]     = b0;
    __syncthreads();

    const int steps = Kslice >> 5;
    for (int s = 0; s < steps; s++) {
        const int cur = s & 1, nxt = cur ^ 1;
        const bool more = (s + 1 < steps);
        if (more) {                           // prefetch tile s+1 (global)
            const int k0 = (s + 1) * 32;
            a0 = *(const uint4*)(Aa + k0);
            a1 = *(const uint4*)(Aa + k0 + 8);
            b0 = *(const uint4*)(Bb + k0);
        }

        bf16x8 af[4], bfr[2];
#pragma unroll
        for (int i = 0; i < 4; i++)
            af[i] = *(const bf16x8*)&As[cur][(wm + i * 16 + ml) * 40 + quad * 8];
#pragma unroll
        for (int j = 0; j < 2; j++)
            bfr[j] = *(const bf16x8*)&Bs[cur][(wn + j * 16 + ml) * 40 + quad * 8];

        if (more) {                           // stage tile s+1 into other buffer
            *(uint4*)&As[nxt][ar * 40 + ac]     = a0;
            *(uint4*)&As[nxt][ar * 40 + ac + 8] = a1;
            *(uint4*)&Bs[nxt][br * 40 + bc]     = b0;
        }

#pragma unroll
        for (int i = 0; i < 4; i++)
#pragma unroll
            for (int j = 0; j < 2; j++)
                acc[i][j] = __builtin_amdgcn_mfma_f32_16x16x32_bf16(
                    af[i], bfr[j], acc[i][j], 0, 0, 0);

        if (more) __syncthreads();            // single barrier per k-step
    }

    unsigned short* op = outp + (size_t)blockIdx.z * zstride;
#pragma unroll
    for (int i = 0; i < 4; i++)
#pragma unroll
        for (int j = 0; j < 2; j++)
#pragma unroll
            for (int r = 0; r < 4; r++) {
                const int row = bm + wm + i * 16 + quad * 4 + r;  // C/D row=quad*4+reg
                const int col = bn + wn + j * 16 + ml;            // C/D col=lane&15
                const float v = acc[i][j][r];
                if (EPI == 0) {
                    op[(size_t)row * N + col] = f2b(v);
                } else if (EPI == 2) {
                    const float u = v + bias[col];
                    const float g = 0.5f * u * (1.0f + erff(u * 0.70710678118654752f));
                    outb[(size_t)row * N + col] = f2b(g);
                } else {
                    // split qkv: col -> (which, head, dim); head-major bf16
                    const int which = col >> 9;
                    const int hh = (col & 511) >> 6;
                    const int dim = col & 63;
                    unsigned short* dst =
                        which == 0 ? outq : (which == 1 ? outk : outv);
                    dst[((size_t)hh * MROWS + row) * HD + dim] = f2b(v);
                }
            }
}

// ---------------------------------------------------------------------------
// Split-K reduce (bf16 partials) + residual + bias, optionally fused with the
// NEXT LayerNorm:  x' = xin + sum_z part[z] + bias;
//                  if DO_LN: h = LN(x')*lns + lnb (bf16)
// One wave per row. Deterministic f32 sum order; in-place xout==xin safe.
// ---------------------------------------------------------------------------
template<bool DO_LN>
__global__ __launch_bounds__(256) void reduce_kernel(
    const float* __restrict__ xin,
    const unsigned short* __restrict__ part,   // [4][MROWS x DM] bf16
    const float* __restrict__ bias,            // DM
    const float* __restrict__ lns, const float* __restrict__ lnb,
    float* __restrict__ xout, unsigned short* __restrict__ h)
{
    const int wid  = blockIdx.x * 4 + (threadIdx.x >> 6);
    const int lane = threadIdx.x & 63;
    const int c0 = lane * 4, c1 = 256 + lane * 4;
    const size_t ro = (size_t)wid * DM;

    float4 a0 = *(const float4*)&xin[ro + c0];
    float4 a1 = *(const float4*)&xin[ro + c1];
#pragma unroll
    for (int z = 0; z < 4; z++) {
        const unsigned short* p = part + (size_t)z * (MROWS * (size_t)DM) + ro;
        const ushort4 p0 = *(const ushort4*)&p[c0];
        const ushort4 p1 = *(const ushort4*)&p[c1];
        a0.x += b2f(p0.x); a0.y += b2f(p0.y); a0.z += b2f(p0.z); a0.w += b2f(p0.w);
        a1.x += b2f(p1.x); a1.y += b2f(p1.y); a1.z += b2f(p1.z); a1.w += b2f(p1.w);
    }
    a0.x += bias[c0+0]; a0.y += bias[c0+1]; a0.z += bias[c0+2]; a0.w += bias[c0+3];
    a1.x += bias[c1+0]; a1.y += bias[c1+1]; a1.z += bias[c1+2]; a1.w += bias[c1+3];

    *(float4*)&xout[ro + c0] = a0;
    *(float4*)&xout[ro + c1] = a1;

    if (DO_LN) {
        float s = a0.x + a0.y + a0.z + a0.w + a1.x + a1.y + a1.z + a1.w;
        float q = a0.x*a0.x + a0.y*a0.y + a0.z*a0.z + a0.w*a0.w
                + a1.x*a1.x + a1.y*a1.y + a1.z*a1.z + a1.w*a1.w;
#pragma unroll
        for (int off = 32; off; off >>= 1) {
            s += __shfl_xor(s, off, 64);
            q += __shfl_xor(q, off, 64);
        }
        const float mean = s * (1.0f / DM);
        const float var  = q * (1.0f / DM) - mean * mean;
        const float rs   = rsqrtf(var + 1e-5f);
        unsigned short* hr = h + ro;
        ushort4 o0, o1;
        o0.x = f2b((a0.x - mean) * rs * lns[c0+0] + lnb[c0+0]);
        o0.y = f2b((a0.y - mean) * rs * lns[c0+1] + lnb[c0+1]);
        o0.z = f2b((a0.z - mean) * rs * lns[c0+2] + lnb[c0+2]);
        o0.w = f2b((a0.w - mean) * rs * lns[c0+3] + lnb[c0+3]);
        o1.x = f2b((a1.x - mean) * rs * lns[c1+0] + lnb[c1+0]);
        o1.y = f2b((a1.y - mean) * rs * lns[c1+1] + lnb[c1+1]);
        o1.z = f2b((a1.z - mean) * rs * lns[c1+2] + lnb[c1+2]);
        o1.w = f2b((a1.w - mean) * rs * lns[c1+3] + lnb[c1+3]);
        *(ushort4*)&hr[c0] = o0;
        *(ushort4*)&hr[c1] = o1;
    }
}

// ---------------------------------------------------------------------------
extern "C" void kernel_launch(void* const* d_in, const int* in_sizes, int n_in,
                              void* d_out, int out_size, void* d_ws, size_t ws_size,
                              hipStream_t stream)
{
    (void)in_sizes; (void)n_in; (void)out_size; (void)ws_size;
    const float* x_in   = (const float*)d_in[0];
    const float* ln1_s  = (const float*)d_in[1];
    const float* ln1_b  = (const float*)d_in[2];
    const float* qkv_w  = (const float*)d_in[3];
    const float* proj_w = (const float*)d_in[4];
    const float* proj_b = (const float*)d_in[5];
    const float* ln2_s  = (const float*)d_in[6];
    const float* ln2_b  = (const float*)d_in[7];
    const float* w1     = (const float*)d_in[8];
    const float* b1     = (const float*)d_in[9];
    const float* w2     = (const float*)d_in[10];
    const float* b2     = (const float*)d_in[11];

    // Workspace carve-up (bytes)
    char* ws = (char*)d_ws;
    float*          xbuf = (float*)(ws);                        //   0 MB, 8 MB
    unsigned short* qhb  = (unsigned short*)(ws + 8388608);     //   8 MB, 4 MB bf16 [8][4096][64]
    unsigned short* khb  = (unsigned short*)(ws + 12582912);    //  12 MB, 4 MB
    unsigned short* vhb  = (unsigned short*)(ws + 16777216);    //  16 MB, 4 MB
    unsigned short* ubuf = (unsigned short*)(ws + 33554432);    //  32 MB, 16 MB bf16
    unsigned short* hbuf = (unsigned short*)(ws + 50331648);    //  48 MB, 4 MB
    unsigned short* obuf = (unsigned short*)(ws + 54525952);    //  52 MB, 4 MB
    unsigned short* part = (unsigned short*)(ws + 58720256);    //  56 MB, 16 MB bf16 [4][4096x512]
    unsigned short* qkvT = (unsigned short*)(ws + 92274688);    //  88 MB
    unsigned short* projT= (unsigned short*)(ws + 96993280);
    unsigned short* w1T  = (unsigned short*)(ws + 98566144);
    unsigned short* w2T  = (unsigned short*)(ws + 104857600);   // ends 106 MB

    const size_t ZS = (size_t)MROWS * DM;   // partial-slice stride (elements)

    hipMemcpyAsync(xbuf, x_in, (size_t)MROWS * DM * sizeof(float),
                   hipMemcpyDeviceToDevice, stream);

    transpose_w_kernel<<<dim3(1536/32, 512/32, 3),  dim3(32, 8), 0, stream>>>(qkv_w,  qkvT, 512, 1536);
    transpose_w_kernel<<<dim3( 512/32, 512/32, 3),  dim3(32, 8), 0, stream>>>(proj_w, projT, 512, 512);
    transpose_w_kernel<<<dim3(2048/32, 512/32, 3),  dim3(32, 8), 0, stream>>>(w1,     w1T,  512, 2048);
    transpose_w_kernel<<<dim3( 512/32, 2048/32, 3), dim3(32, 8), 0, stream>>>(w2,     w2T, 2048, 512);

    // depth-0 LN1 (later LNs fused into reduce_kernel)
    ln_kernel<<<MROWS / 4, 256, 0, stream>>>(xbuf, ln1_s, ln1_b, hbuf);

    for (int d = 0; d < NDEPTH; d++) {
        const int dil = 1 << d;

        // qkv = h @ qkv_w -> head-major bf16 q/k/v. grid (24,32) = 768 blocks.
        gemm_kernel<3><<<dim3(1536/64, MROWS/128, 1), 256, 0, stream>>>(
            hbuf, qkvT + (size_t)d * 1536 * 512, nullptr, nullptr, nullptr,
            qhb, khb, vhb, 1536, 512, 512, 0);
        // dilated attention -> o (bf16)
        attn_kernel<<<2 * NH * (TSEQ / 16), 256, 0, stream>>>(qhb, khb, vhb, obuf, dil);
        // proj partials (bf16): split-K x4, Kslice 128. grid (8,32,4) = 1024 blocks.
        gemm_kernel<0><<<dim3(512/64, MROWS/128, 4), 256, 0, stream>>>(
            obuf, projT + (size_t)d * 512 * 512, nullptr, part, nullptr,
            nullptr, nullptr, nullptr, 512, 512, 128, ZS);
        // x += sum(part) + proj_b ; h = LN2(x) fused
        reduce_kernel<true><<<MROWS / 4, 256, 0, stream>>>(
            xbuf, part, proj_b + d * DM, ln2_s + d * DM, ln2_b + d * DM,
            xbuf, hbuf);
        // u = gelu(h @ w1 + b1). grid (32,32) = 1024 blocks.
        gemm_kernel<2><<<dim3(2048/64, MROWS/128, 1), 256, 0, stream>>>(
            hbuf, w1T + (size_t)d * 2048 * 512, b1 + d * 2048, nullptr, ubuf,
            nullptr, nullptr, nullptr, 2048, 512, 512, 0);
        // w2 partials (bf16): split-K x4, Kslice 512. grid (8,32,4) = 1024 blocks.
        gemm_kernel<0><<<dim3(512/64, MROWS/128, 4), 256, 0, stream>>>(
            ubuf, w2T + (size_t)d * 512 * 2048, nullptr, part, nullptr,
            nullptr, nullptr, nullptr, 512, 2048, 512, ZS);
        // x += sum(part) + b2 ; fuse next depth's LN1 (or final write to d_out)
        if (d < NDEPTH - 1) {
            reduce_kernel<true><<<MROWS / 4, 256, 0, stream>>>(
                xbuf, part, b2 + d * DM, ln1_s + (d+1) * DM, ln1_b + (d+1) * DM,
                xbuf, hbuf);
        } else {
            reduce_kernel<false><<<MROWS / 4, 256, 0, stream>>>(
                xbuf, part, b2 + d * DM, nullptr, nullptr,
                (float*)d_out, nullptr);
        }
    }
}

// Round 11
// 415.215 us; speedup vs baseline: 1.9021x; 1.0313x over previous
//
#include <hip/hip_runtime.h>
#include <math.h>

// Problem constants (B=2, T=2048, D=512, H=8, hd=64, K=16, DEPTH=3)
#define TSEQ   2048
#define DM     512
#define NH     8
#define HD     64
#define KATT   16
#define NDEPTH 3
#define MROWS  4096   // B*T

typedef __attribute__((ext_vector_type(8))) short bf16x8;
typedef __attribute__((ext_vector_type(8))) unsigned short u16x8;
typedef __attribute__((ext_vector_type(4))) float f32x4;

// f32 -> bf16 (round-to-nearest-even), bit-level
static __device__ __forceinline__ unsigned short f2b(float f) {
    unsigned int u = __float_as_uint(f);
    unsigned int r = (u + 0x7fffu + ((u >> 16) & 1u)) >> 16;
    return (unsigned short)r;
}
// bf16 bits -> f32
static __device__ __forceinline__ float b2f(unsigned short s) {
    return __uint_as_float((unsigned int)s << 16);
}

// ---------------------------------------------------------------------------
// Weight prep: W f32 [K x N] (per depth) -> Wt bf16 [N x K]. grid.z = depth.
// ---------------------------------------------------------------------------
__global__ __launch_bounds__(256) void transpose_w_kernel(
    const float* __restrict__ W, unsigned short* __restrict__ Wt, int Kd, int Nd)
{
    __shared__ float tile[32][33];
    const int n0 = blockIdx.x * 32, k0 = blockIdx.y * 32;
    const size_t off = (size_t)blockIdx.z * Kd * Nd;
    const float* Wd = W + off;
    unsigned short* Wtd = Wt + off;
    const int tx = threadIdx.x, ty = threadIdx.y;
#pragma unroll
    for (int r = 0; r < 32; r += 8)
        tile[ty + r][tx] = Wd[(size_t)(k0 + ty + r) * Nd + (n0 + tx)];
    __syncthreads();
#pragma unroll
    for (int r = 0; r < 32; r += 8)
        Wtd[(size_t)(n0 + ty + r) * Kd + (k0 + tx)] = f2b(tile[tx][ty + r]);
}

// ---------------------------------------------------------------------------
// LayerNorm: x f32 [4096 x 512] -> h bf16 [4096 x 512]. One wave per row.
// (only used for depth-0 LN1; later LNs are fused into reduce_kernel)
// ---------------------------------------------------------------------------
__global__ __launch_bounds__(256) void ln_kernel(
    const float* __restrict__ x, const float* __restrict__ sc,
    const float* __restrict__ bi, unsigned short* __restrict__ h)
{
    const int wid  = blockIdx.x * 4 + (threadIdx.x >> 6);
    const int lane = threadIdx.x & 63;
    const float* xr = x + (size_t)wid * DM;
    const float4 v0 = *(const float4*)&xr[lane * 4];
    const float4 v1 = *(const float4*)&xr[256 + lane * 4];
    float s = v0.x + v0.y + v0.z + v0.w + v1.x + v1.y + v1.z + v1.w;
    float q = v0.x*v0.x + v0.y*v0.y + v0.z*v0.z + v0.w*v0.w
            + v1.x*v1.x + v1.y*v1.y + v1.z*v1.z + v1.w*v1.w;
#pragma unroll
    for (int off = 32; off; off >>= 1) {
        s += __shfl_xor(s, off, 64);
        q += __shfl_xor(q, off, 64);
    }
    const float mean = s * (1.0f / DM);
    const float var  = q * (1.0f / DM) - mean * mean;
    const float rs   = rsqrtf(var + 1e-5f);
    unsigned short* hr = h + (size_t)wid * DM;
    const int c0 = lane * 4, c1 = 256 + lane * 4;
    ushort4 o0, o1;
    o0.x = f2b((v0.x - mean) * rs * sc[c0+0] + bi[c0+0]);
    o0.y = f2b((v0.y - mean) * rs * sc[c0+1] + bi[c0+1]);
    o0.z = f2b((v0.z - mean) * rs * sc[c0+2] + bi[c0+2]);
    o0.w = f2b((v0.w - mean) * rs * sc[c0+3] + bi[c0+3]);
    o1.x = f2b((v1.x - mean) * rs * sc[c1+0] + bi[c1+0]);
    o1.y = f2b((v1.y - mean) * rs * sc[c1+1] + bi[c1+1]);
    o1.z = f2b((v1.z - mean) * rs * sc[c1+2] + bi[c1+2]);
    o1.w = f2b((v1.w - mean) * rs * sc[c1+3] + bi[c1+3]);
    *(ushort4*)&hr[c0] = o0;
    *(ushort4*)&hr[c1] = o1;
}

// ---------------------------------------------------------------------------
// Dilated attention over head-major bf16 q/k/v slabs (R6 design, proven).
// ---------------------------------------------------------------------------
__global__ __launch_bounds__(256) void attn_kernel(
    const unsigned short* __restrict__ qh, const unsigned short* __restrict__ kh,
    const unsigned short* __restrict__ vh, unsigned short* __restrict__ o, int dil)
{
    const int blk  = blockIdx.x;
    const int tile = blk & (TSEQ / 16 - 1);   // 128 query tiles
    const int bh   = blk >> 7;
    const int b    = bh >> 3, hh = bh & 7;
    const int t0   = tile * 16;
    const int wave = threadIdx.x >> 6, lane = threadIdx.x & 63;
    const int tq   = wave * 4 + (lane >> 4);  // query 0..15
    const int s    = lane & 15;               // key slot 0..15
    const int t    = t0 + tq;
    const size_t slab = ((size_t)hh * MROWS + (size_t)b * TSEQ) * HD;

    __shared__ float p_lds[16][17];

    // ---- phase 1: scores + softmax ----
    int row = t - s * dil;
    const bool valid = (row >= 0);
    row = max(row, 0);
    const u16x8* kr = (const u16x8*)(kh + slab + (size_t)row * HD);
    const u16x8* qr = (const u16x8*)(qh + slab + (size_t)t * HD);
    float dot = 0.0f;
#pragma unroll
    for (int j = 0; j < 8; j++) {
        const u16x8 kk = kr[j];
        const u16x8 qq = qr[j];
#pragma unroll
        for (int e = 0; e < 8; e++) dot += b2f(qq[e]) * b2f(kk[e]);
    }
    const float sc = valid ? dot * 0.125f : -1e30f;
    float m = sc;
#pragma unroll
    for (int off = 1; off < 16; off <<= 1) m = fmaxf(m, __shfl_xor(m, off, 64));
    const float p = expf(sc - m);
    float l = p;
#pragma unroll
    for (int off = 1; off < 16; off <<= 1) l += __shfl_xor(l, off, 64);
    p_lds[tq][s] = p / l;
    __syncthreads();

    // ---- phase 2: o = sum_s p * v (lane = dim) ----
#pragma unroll
    for (int qi = 0; qi < 4; qi++) {
        const int qq = qi * 4 + wave;
        const int tt = t0 + qq;
        float acc = 0.0f;
#pragma unroll
        for (int ss = 0; ss < KATT; ss++) {
            int vr = tt - ss * dil;
            const float pw = p_lds[qq][ss];   // exactly 0 for masked slots
            vr = max(vr, 0);
            acc += pw * b2f(vh[slab + (size_t)vr * HD + lane]);
        }
        o[(size_t)(b * TSEQ + tt) * DM + (size_t)hh * HD + lane] = f2b(acc);
    }
}

// ---------------------------------------------------------------------------
// GEMM (R9 dbuf structure, tile-templated): C = A_bf16[M,K] * Bt[N,K]^T over
// K-slice z. BK=32, block 128 x TN, 4 waves (2x2), wave tile 64 x TN/2.
//   TN=64  (qkv/proj): per wave-step  8 MFMA : 6 ds_read_b128 (R8/R9 proven)
//   TN=128 (w1/w2):    per wave-step 16 MFMA : 8 ds_read_b128 — 1.8x less
//     LDS-pipe clk per FLOP (the R9-identified bottleneck). Occupancy audit:
//     grid 512 blocks = 2 blocks/CU x 4 waves = 8 waves/CU; VGPR ~130-160
//     (acc 64) = 2 waves/SIMD bin -> exactly 8 resident. No spill expected
//     (R7 lesson: watch WRITE_SIZE).
// LDS stride 40 shorts (80 B -> full bank spread, 0 conflicts). Double-
// buffered, prefetch at step top, ONE barrier per k-step.
//   EPI 0: outp[z*zstride + idx] = bf16(C)   (proj/w2 partials, bf16)
//   EPI 2: outb = bf16(gelu(C + bias))       (w1, exact gelu)
//   EPI 3: split qkv -> head-major bf16 q/k/v slabs
// ---------------------------------------------------------------------------
template<int EPI, int TN>
__global__ __launch_bounds__(256) void gemm_kernel(
    const unsigned short* __restrict__ A,   // M x K
    const unsigned short* __restrict__ Bt,  // N x K
    const float* __restrict__ bias,         // N (EPI 2 only)
    unsigned short* __restrict__ outp,      // bf16 partials (EPI 0)
    unsigned short* __restrict__ outb,      // bf16 out (EPI 2)
    unsigned short* __restrict__ outq,      // EPI 3
    unsigned short* __restrict__ outk,      // EPI 3
    unsigned short* __restrict__ outv,      // EPI 3
    int N, int K, int Kslice, size_t zstride)
{
    constexpr int FN = TN / 32;               // B frags per wave (2 or 4)
    const int tid  = threadIdx.x;
    const int wave = tid >> 6, lane = tid & 63;
    const int bm = blockIdx.y * 128;
    const int bn = blockIdx.x * TN;
    const int wm = (wave >> 1) * 64;          // wave rows: 64
    const int wn = (wave & 1) * (TN / 2);     // wave cols: TN/2
    const int ml = lane & 15, quad = lane >> 4;
    const int kbeg = blockIdx.z * Kslice;

    __shared__ unsigned short As[2][128 * 40];
    __shared__ unsigned short Bs[2][TN * 40];

    f32x4 acc[4][FN] = {};

    // A staging: row ar=tid>>1, 32B chunk ac=(tid&1)*16 (2 uint4 / thread)
    const int ar = tid >> 1, ac = (tid & 1) * 16;
    // B staging: TN=64: row tid>>2, 16B seg (tid&3)*8 (1 uint4 / thread)
    //            TN=128: row tid>>1, 32B chunk (tid&1)*16 (2 uint4 / thread)
    const int br = (TN == 64) ? (tid >> 2) : (tid >> 1);
    const int bc = (TN == 64) ? (tid & 3) * 8 : (tid & 1) * 16;
    const unsigned short* Aa = A  + (size_t)(bm + ar) * K + kbeg + ac;
    const unsigned short* Bb = Bt + (size_t)(bn + br) * K + kbeg + bc;

    // preload tile 0 into buffer 0
    uint4 a0 = *(const uint4*)(Aa);
    uint4 a1 = *(const uint4*)(Aa + 8);
    uint4 b0 = *(const uint4*)(Bb);
    uint4 b1;
    if (TN == 128) b1 = *(const uint4*)(Bb + 8);
    *(uint4*)&As[0][ar * 40 + ac]     = a0;
    *(uint4*)&As[0][ar * 40 + ac + 8] = a1;
    *(uint4*)&Bs[0][br * 40 + bc]     = b0;
    if (TN == 128) *(uint4*)&Bs[0][br * 40 + bc + 8] = b1;
    __syncthreads();

    const int steps = Kslice >> 5;
    for (int s = 0; s < steps; s++) {
        const int cur = s & 1, nxt = cur ^ 1;
        const bool more = (s + 1 < steps);
        if (more) {                           // prefetch tile s+1 (global)
            const int k0 = (s + 1) * 32;
            a0 = *(const uint4*)(Aa + k0);
            a1 = *(const uint4*)(Aa + k0 + 8);
            b0 = *(const uint4*)(Bb + k0);
            if (TN == 128) b1 = *(const uint4*)(Bb + k0 + 8);
        }

        bf16x8 af[4], bfr[FN];
#pragma unroll
        for (int i = 0; i < 4; i++)
            af[i] = *(const bf16x8*)&As[cur][(wm + i * 16 + ml) * 40 + quad * 8];
#pragma unroll
        for (int j = 0; j < FN; j++)
            bfr[j] = *(const bf16x8*)&Bs[cur][(wn + j * 16 + ml) * 40 + quad * 8];

        if (more) {                           // stage tile s+1 into other buffer
            *(uint4*)&As[nxt][ar * 40 + ac]     = a0;
            *(uint4*)&As[nxt][ar * 40 + ac + 8] = a1;
            *(uint4*)&Bs[nxt][br * 40 + bc]     = b0;
            if (TN == 128) *(uint4*)&Bs[nxt][br * 40 + bc + 8] = b1;
        }

#pragma unroll
        for (int i = 0; i < 4; i++)
#pragma unroll
            for (int j = 0; j < FN; j++)
                acc[i][j] = __builtin_amdgcn_mfma_f32_16x16x32_bf16(
                    af[i], bfr[j], acc[i][j], 0, 0, 0);

        if (more) __syncthreads();            // single barrier per k-step
    }

    unsigned short* op = outp + (size_t)blockIdx.z * zstride;
#pragma unroll
    for (int i = 0; i < 4; i++)
#pragma unroll
        for (int j = 0; j < FN; j++)
#pragma unroll
            for (int r = 0; r < 4; r++) {
                const int row = bm + wm + i * 16 + quad * 4 + r;  // C/D row=quad*4+reg
                const int col = bn + wn + j * 16 + ml;            // C/D col=lane&15
                const float v = acc[i][j][r];
                if (EPI == 0) {
                    op[(size_t)row * N + col] = f2b(v);
                } else if (EPI == 2) {
                    const float u = v + bias[col];
                    const float g = 0.5f * u * (1.0f + erff(u * 0.70710678118654752f));
                    outb[(size_t)row * N + col] = f2b(g);
                } else {
                    // split qkv: col -> (which, head, dim); head-major bf16
                    const int which = col >> 9;
                    const int hh = (col & 511) >> 6;
                    const int dim = col & 63;
                    unsigned short* dst =
                        which == 0 ? outq : (which == 1 ? outk : outv);
                    dst[((size_t)hh * MROWS + row) * HD + dim] = f2b(v);
                }
            }
}

// ---------------------------------------------------------------------------
// Split-K reduce (bf16 partials) + residual + bias, optionally fused with the
// NEXT LayerNorm:  x' = xin + sum_z part[z] + bias;
//                  if DO_LN: h = LN(x')*lns + lnb (bf16)
// One wave per row. Deterministic f32 sum order; in-place xout==xin safe.
// ---------------------------------------------------------------------------
template<bool DO_LN>
__global__ __launch_bounds__(256) void reduce_kernel(
    const float* __restrict__ xin,
    const unsigned short* __restrict__ part,   // [4][MROWS x DM] bf16
    const float* __restrict__ bias,            // DM
    const float* __restrict__ lns, const float* __restrict__ lnb,
    float* __restrict__ xout, unsigned short* __restrict__ h)
{
    const int wid  = blockIdx.x * 4 + (threadIdx.x >> 6);
    const int lane = threadIdx.x & 63;
    const int c0 = lane * 4, c1 = 256 + lane * 4;
    const size_t ro = (size_t)wid * DM;

    float4 a0 = *(const float4*)&xin[ro + c0];
    float4 a1 = *(const float4*)&xin[ro + c1];
#pragma unroll
    for (int z = 0; z < 4; z++) {
        const unsigned short* p = part + (size_t)z * (MROWS * (size_t)DM) + ro;
        const ushort4 p0 = *(const ushort4*)&p[c0];
        const ushort4 p1 = *(const ushort4*)&p[c1];
        a0.x += b2f(p0.x); a0.y += b2f(p0.y); a0.z += b2f(p0.z); a0.w += b2f(p0.w);
        a1.x += b2f(p1.x); a1.y += b2f(p1.y); a1.z += b2f(p1.z); a1.w += b2f(p1.w);
    }
    a0.x += bias[c0+0]; a0.y += bias[c0+1]; a0.z += bias[c0+2]; a0.w += bias[c0+3];
    a1.x += bias[c1+0]; a1.y += bias[c1+1]; a1.z += bias[c1+2]; a1.w += bias[c1+3];

    *(float4*)&xout[ro + c0] = a0;
    *(float4*)&xout[ro + c1] = a1;

    if (DO_LN) {
        float s = a0.x + a0.y + a0.z + a0.w + a1.x + a1.y + a1.z + a1.w;
        float q = a0.x*a0.x + a0.y*a0.y + a0.z*a0.z + a0.w*a0.w
                + a1.x*a1.x + a1.y*a1.y + a1.z*a1.z + a1.w*a1.w;
#pragma unroll
        for (int off = 32; off; off >>= 1) {
            s += __shfl_xor(s, off, 64);
            q += __shfl_xor(q, off, 64);
        }
        const float mean = s * (1.0f / DM);
        const float var  = q * (1.0f / DM) - mean * mean;
        const float rs   = rsqrtf(var + 1e-5f);
        unsigned short* hr = h + ro;
        ushort4 o0, o1;
        o0.x = f2b((a0.x - mean) * rs * lns[c0+0] + lnb[c0+0]);
        o0.y = f2b((a0.y - mean) * rs * lns[c0+1] + lnb[c0+1]);
        o0.z = f2b((a0.z - mean) * rs * lns[c0+2] + lnb[c0+2]);
        o0.w = f2b((a0.w - mean) * rs * lns[c0+3] + lnb[c0+3]);
        o1.x = f2b((a1.x - mean) * rs * lns[c1+0] + lnb[c1+0]);
        o1.y = f2b((a1.y - mean) * rs * lns[c1+1] + lnb[c1+1]);
        o1.z = f2b((a1.z - mean) * rs * lns[c1+2] + lnb[c1+2]);
        o1.w = f2b((a1.w - mean) * rs * lns[c1+3] + lnb[c1+3]);
        *(ushort4*)&hr[c0] = o0;
        *(ushort4*)&hr[c1] = o1;
    }
}

// ---------------------------------------------------------------------------
extern "C" void kernel_launch(void* const* d_in, const int* in_sizes, int n_in,
                              void* d_out, int out_size, void* d_ws, size_t ws_size,
                              hipStream_t stream)
{
    (void)in_sizes; (void)n_in; (void)out_size; (void)ws_size;
    const float* x_in   = (const float*)d_in[0];
    const float* ln1_s  = (const float*)d_in[1];
    const float* ln1_b  = (const float*)d_in[2];
    const float* qkv_w  = (const float*)d_in[3];
    const float* proj_w = (const float*)d_in[4];
    const float* proj_b = (const float*)d_in[5];
    const float* ln2_s  = (const float*)d_in[6];
    const float* ln2_b  = (const float*)d_in[7];
    const float* w1     = (const float*)d_in[8];
    const float* b1     = (const float*)d_in[9];
    const float* w2     = (const float*)d_in[10];
    const float* b2     = (const float*)d_in[11];

    // Workspace carve-up (bytes)
    char* ws = (char*)d_ws;
    float*          xbuf = (float*)(ws);                        //   0 MB, 8 MB
    unsigned short* qhb  = (unsigned short*)(ws + 8388608);     //   8 MB, 4 MB bf16 [8][4096][64]
    unsigned short* khb  = (unsigned short*)(ws + 12582912);    //  12 MB, 4 MB
    unsigned short* vhb  = (unsigned short*)(ws + 16777216);    //  16 MB, 4 MB
    unsigned short* ubuf = (unsigned short*)(ws + 33554432);    //  32 MB, 16 MB bf16
    unsigned short* hbuf = (unsigned short*)(ws + 50331648);    //  48 MB, 4 MB
    unsigned short* obuf = (unsigned short*)(ws + 54525952);    //  52 MB, 4 MB
    unsigned short* part = (unsigned short*)(ws + 58720256);    //  56 MB, 16 MB bf16 [4][4096x512]
    unsigned short* qkvT = (unsigned short*)(ws + 92274688);    //  88 MB
    unsigned short* projT= (unsigned short*)(ws + 96993280);
    unsigned short* w1T  = (unsigned short*)(ws + 98566144);
    unsigned short* w2T  = (unsigned short*)(ws + 104857600);   // ends 106 MB

    const size_t ZS = (size_t)MROWS * DM;   // partial-slice stride (elements)

    hipMemcpyAsync(xbuf, x_in, (size_t)MROWS * DM * sizeof(float),
                   hipMemcpyDeviceToDevice, stream);

    transpose_w_kernel<<<dim3(1536/32, 512/32, 3),  dim3(32, 8), 0, stream>>>(qkv_w,  qkvT, 512, 1536);
    transpose_w_kernel<<<dim3( 512/32, 512/32, 3),  dim3(32, 8), 0, stream>>>(proj_w, projT, 512, 512);
    transpose_w_kernel<<<dim3(2048/32, 512/32, 3),  dim3(32, 8), 0, stream>>>(w1,     w1T,  512, 2048);
    transpose_w_kernel<<<dim3( 512/32, 2048/32, 3), dim3(32, 8), 0, stream>>>(w2,     w2T, 2048, 512);

    // depth-0 LN1 (later LNs fused into reduce_kernel)
    ln_kernel<<<MROWS / 4, 256, 0, stream>>>(xbuf, ln1_s, ln1_b, hbuf);

    for (int d = 0; d < NDEPTH; d++) {
        const int dil = 1 << d;

        // qkv = h @ qkv_w -> head-major bf16 q/k/v. grid (24,32) = 768 blocks.
        gemm_kernel<3, 64><<<dim3(1536/64, MROWS/128, 1), 256, 0, stream>>>(
            hbuf, qkvT + (size_t)d * 1536 * 512, nullptr, nullptr, nullptr,
            qhb, khb, vhb, 1536, 512, 512, 0);
        // dilated attention -> o (bf16)
        attn_kernel<<<2 * NH * (TSEQ / 16), 256, 0, stream>>>(qhb, khb, vhb, obuf, dil);
        // proj partials (bf16): split-K x4, Kslice 128. grid (8,32,4) = 1024 blocks.
        gemm_kernel<0, 64><<<dim3(512/64, MROWS/128, 4), 256, 0, stream>>>(
            obuf, projT + (size_t)d * 512 * 512, nullptr, part, nullptr,
            nullptr, nullptr, nullptr, 512, 512, 128, ZS);
        // x += sum(part) + proj_b ; h = LN2(x) fused
        reduce_kernel<true><<<MROWS / 4, 256, 0, stream>>>(
            xbuf, part, proj_b + d * DM, ln2_s + d * DM, ln2_b + d * DM,
            xbuf, hbuf);
        // u = gelu(h @ w1 + b1). TN=128: grid (16,32) = 512 blocks, 8 waves/CU.
        gemm_kernel<2, 128><<<dim3(2048/128, MROWS/128, 1), 256, 0, stream>>>(
            hbuf, w1T + (size_t)d * 2048 * 512, b1 + d * 2048, nullptr, ubuf,
            nullptr, nullptr, nullptr, 2048, 512, 512, 0);
        // w2 partials (bf16): split-K x4, Kslice 512. TN=128: grid (4,32,4) = 512.
        gemm_kernel<0, 128><<<dim3(512/128, MROWS/128, 4), 256, 0, stream>>>(
            ubuf, w2T + (size_t)d * 512 * 2048, nullptr, part, nullptr,
            nullptr, nullptr, nullptr, 512, 2048, 512, ZS);
        // x += sum(part) + b2 ; fuse next depth's LN1 (or final write to d_out)
        if (d < NDEPTH - 1) {
            reduce_kernel<true><<<MROWS / 4, 256, 0, stream>>>(
                xbuf, part, b2 + d * DM, ln1_s + (d+1) * DM, ln1_b + (d+1) * DM,
                xbuf, hbuf);
        } else {
            reduce_kernel<false><<<MROWS / 4, 256, 0, stream>>>(
                xbuf, part, b2 + d * DM, nullptr, nullptr,
                (float*)d_out, nullptr);
        }
    }
}

// Round 12
// 406.551 us; speedup vs baseline: 1.9426x; 1.0213x over previous
//
#include <hip/hip_runtime.h>
#include <math.h>

// Problem constants (B=2, T=2048, D=512, H=8, hd=64, K=16, DEPTH=3)
#define TSEQ   2048
#define DM     512
#define NH     8
#define HD     64
#define KATT   16
#define NDEPTH 3
#define MROWS  4096   // B*T

typedef __attribute__((ext_vector_type(8))) short bf16x8;
typedef __attribute__((ext_vector_type(8))) unsigned short u16x8;
typedef __attribute__((ext_vector_type(4))) float f32x4;

// f32 -> bf16 (round-to-nearest-even), bit-level
static __device__ __forceinline__ unsigned short f2b(float f) {
    unsigned int u = __float_as_uint(f);
    unsigned int r = (u + 0x7fffu + ((u >> 16) & 1u)) >> 16;
    return (unsigned short)r;
}
// bf16 bits -> f32
static __device__ __forceinline__ float b2f(unsigned short s) {
    return __uint_as_float((unsigned int)s << 16);
}

// global -> LDS direct DMA, 16 B per lane; HW writes lane i at lds + i*16.
static __device__ __forceinline__ void load_lds16(const void* g, void* l) {
    __builtin_amdgcn_global_load_lds(
        (const __attribute__((address_space(1))) unsigned int*)g,
        (__attribute__((address_space(3))) unsigned int*)l, 16, 0, 0);
}

// ---------------------------------------------------------------------------
// Weight prep: W f32 [K x N] (per depth) -> Wt bf16 [N x K]. grid.z = depth.
// ---------------------------------------------------------------------------
__global__ __launch_bounds__(256) void transpose_w_kernel(
    const float* __restrict__ W, unsigned short* __restrict__ Wt, int Kd, int Nd)
{
    __shared__ float tile[32][33];
    const int n0 = blockIdx.x * 32, k0 = blockIdx.y * 32;
    const size_t off = (size_t)blockIdx.z * Kd * Nd;
    const float* Wd = W + off;
    unsigned short* Wtd = Wt + off;
    const int tx = threadIdx.x, ty = threadIdx.y;
#pragma unroll
    for (int r = 0; r < 32; r += 8)
        tile[ty + r][tx] = Wd[(size_t)(k0 + ty + r) * Nd + (n0 + tx)];
    __syncthreads();
#pragma unroll
    for (int r = 0; r < 32; r += 8)
        Wtd[(size_t)(n0 + ty + r) * Kd + (k0 + tx)] = f2b(tile[tx][ty + r]);
}

// ---------------------------------------------------------------------------
// LayerNorm: x f32 [4096 x 512] -> h bf16 [4096 x 512]. One wave per row.
// (only used for depth-0 LN1; later LNs are fused into reduce_kernel)
// ---------------------------------------------------------------------------
__global__ __launch_bounds__(256) void ln_kernel(
    const float* __restrict__ x, const float* __restrict__ sc,
    const float* __restrict__ bi, unsigned short* __restrict__ h)
{
    const int wid  = blockIdx.x * 4 + (threadIdx.x >> 6);
    const int lane = threadIdx.x & 63;
    const float* xr = x + (size_t)wid * DM;
    const float4 v0 = *(const float4*)&xr[lane * 4];
    const float4 v1 = *(const float4*)&xr[256 + lane * 4];
    float s = v0.x + v0.y + v0.z + v0.w + v1.x + v1.y + v1.z + v1.w;
    float q = v0.x*v0.x + v0.y*v0.y + v0.z*v0.z + v0.w*v0.w
            + v1.x*v1.x + v1.y*v1.y + v1.z*v1.z + v1.w*v1.w;
#pragma unroll
    for (int off = 32; off; off >>= 1) {
        s += __shfl_xor(s, off, 64);
        q += __shfl_xor(q, off, 64);
    }
    const float mean = s * (1.0f / DM);
    const float var  = q * (1.0f / DM) - mean * mean;
    const float rs   = rsqrtf(var + 1e-5f);
    unsigned short* hr = h + (size_t)wid * DM;
    const int c0 = lane * 4, c1 = 256 + lane * 4;
    ushort4 o0, o1;
    o0.x = f2b((v0.x - mean) * rs * sc[c0+0] + bi[c0+0]);
    o0.y = f2b((v0.y - mean) * rs * sc[c0+1] + bi[c0+1]);
    o0.z = f2b((v0.z - mean) * rs * sc[c0+2] + bi[c0+2]);
    o0.w = f2b((v0.w - mean) * rs * sc[c0+3] + bi[c0+3]);
    o1.x = f2b((v1.x - mean) * rs * sc[c1+0] + bi[c1+0]);
    o1.y = f2b((v1.y - mean) * rs * sc[c1+1] + bi[c1+1]);
    o1.z = f2b((v1.z - mean) * rs * sc[c1+2] + bi[c1+2]);
    o1.w = f2b((v1.w - mean) * rs * sc[c1+3] + bi[c1+3]);
    *(ushort4*)&hr[c0] = o0;
    *(ushort4*)&hr[c1] = o1;
}

// ---------------------------------------------------------------------------
// Dilated attention over head-major bf16 q/k/v slabs (R6 design, proven).
// ---------------------------------------------------------------------------
__global__ __launch_bounds__(256) void attn_kernel(
    const unsigned short* __restrict__ qh, const unsigned short* __restrict__ kh,
    const unsigned short* __restrict__ vh, unsigned short* __restrict__ o, int dil)
{
    const int blk  = blockIdx.x;
    const int tile = blk & (TSEQ / 16 - 1);   // 128 query tiles
    const int bh   = blk >> 7;
    const int b    = bh >> 3, hh = bh & 7;
    const int t0   = tile * 16;
    const int wave = threadIdx.x >> 6, lane = threadIdx.x & 63;
    const int tq   = wave * 4 + (lane >> 4);  // query 0..15
    const int s    = lane & 15;               // key slot 0..15
    const int t    = t0 + tq;
    const size_t slab = ((size_t)hh * MROWS + (size_t)b * TSEQ) * HD;

    __shared__ float p_lds[16][17];

    // ---- phase 1: scores + softmax ----
    int row = t - s * dil;
    const bool valid = (row >= 0);
    row = max(row, 0);
    const u16x8* kr = (const u16x8*)(kh + slab + (size_t)row * HD);
    const u16x8* qr = (const u16x8*)(qh + slab + (size_t)t * HD);
    float dot = 0.0f;
#pragma unroll
    for (int j = 0; j < 8; j++) {
        const u16x8 kk = kr[j];
        const u16x8 qq = qr[j];
#pragma unroll
        for (int e = 0; e < 8; e++) dot += b2f(qq[e]) * b2f(kk[e]);
    }
    const float sc = valid ? dot * 0.125f : -1e30f;
    float m = sc;
#pragma unroll
    for (int off = 1; off < 16; off <<= 1) m = fmaxf(m, __shfl_xor(m, off, 64));
    const float p = expf(sc - m);
    float l = p;
#pragma unroll
    for (int off = 1; off < 16; off <<= 1) l += __shfl_xor(l, off, 64);
    p_lds[tq][s] = p / l;
    __syncthreads();

    // ---- phase 2: o = sum_s p * v (lane = dim) ----
#pragma unroll
    for (int qi = 0; qi < 4; qi++) {
        const int qq = qi * 4 + wave;
        const int tt = t0 + qq;
        float acc = 0.0f;
#pragma unroll
        for (int ss = 0; ss < KATT; ss++) {
            int vr = tt - ss * dil;
            const float pw = p_lds[qq][ss];   // exactly 0 for masked slots
            vr = max(vr, 0);
            acc += pw * b2f(vh[slab + (size_t)vr * HD + lane]);
        }
        o[(size_t)(b * TSEQ + tt) * DM + (size_t)hh * HD + lane] = f2b(acc);
    }
}

// ---------------------------------------------------------------------------
// GEMM (R10 dbuf structure + global_load_lds staging): C = A_bf16[M,K] *
// Bt[N,K]^T over K-slice z. BK=32, block 128 x TN, 4 waves (2x2), wave tile
// 64 x TN/2. Staging is now direct global->LDS DMA (16 B/lane, m97 pattern):
// no staging VGPRs, no ds_write instrs, no VALU staging address work.
// LDS layout (forced by lane*16 placement): unpadded 64 B rows, 16-row
// chunks. K-segment swizzle (R3-verified): stage lane i=4r+s sources k-seg
// (s-(r>>1))&3, reader uses slot (quad+(ml>>1))&3 -> 2-way bank aliasing
// only (free, m136). Double-buffered: async loads for tile s+1 issue at
// step top into buf nxt, ONE __syncthreads per step drains them (vmcnt 0)
// after cur-buffer MFMA. Occupancy: TN=128 LDS 32 KB -> 5 blocks/CU cap;
// grids give 2-4 blocks/CU (R5 lesson: >= 8 waves/CU everywhere).
//   EPI 0: outp[z*zstride + idx] = bf16(C)   (proj/w2 partials, bf16)
//   EPI 2: outb = bf16(gelu(C + bias))       (w1, exact gelu)
//   EPI 3: split qkv -> head-major bf16 q/k/v slabs
// ---------------------------------------------------------------------------
template<int EPI, int TN>
__global__ __launch_bounds__(256) void gemm_kernel(
    const unsigned short* __restrict__ A,   // M x K
    const unsigned short* __restrict__ Bt,  // N x K
    const float* __restrict__ bias,         // N (EPI 2 only)
    unsigned short* __restrict__ outp,      // bf16 partials (EPI 0)
    unsigned short* __restrict__ outb,      // bf16 out (EPI 2)
    unsigned short* __restrict__ outq,      // EPI 3
    unsigned short* __restrict__ outk,      // EPI 3
    unsigned short* __restrict__ outv,      // EPI 3
    int N, int K, int Kslice, size_t zstride)
{
    constexpr int FN = TN / 32;               // B frags per wave (2 or 4)
    constexpr int CA = 2;                     // A 16-row chunks per wave (128/16/4)
    constexpr int CB = TN / 64;               // B chunks per wave (1 or 2)
    const int tid  = threadIdx.x;
    const int wave = tid >> 6, lane = tid & 63;
    const int bm = blockIdx.y * 128;
    const int bn = blockIdx.x * TN;
    const int wm = (wave >> 1) * 64;          // wave rows: 64
    const int wn = (wave & 1) * (TN / 2);     // wave cols: TN/2
    const int ml = lane & 15, quad = lane >> 4;
    const int kbeg = blockIdx.z * Kslice;

    __shared__ unsigned short As[2][128 * 32];   // unpadded: 2 x 8 KB
    __shared__ unsigned short Bs[2][TN * 32];    // unpadded: 2 x TN*64 B

    f32x4 acc[4][FN] = {};

    // staging source: lane i=4r+s -> LDS (row r, 16B slot s) of its chunk;
    // source k-seg c with s = (c + (r>>1)) & 3  (R3-verified swizzle)
    const int rr = lane >> 2, ss = lane & 3;
    const int cc = ((ss - (rr >> 1)) & 3) * 8;   // shorts
    const unsigned short* Aa[CA];
    const unsigned short* Bb[CB];
#pragma unroll
    for (int j = 0; j < CA; j++)
        Aa[j] = A + (size_t)(bm + (wave * CA + j) * 16 + rr) * K + kbeg + cc;
#pragma unroll
    for (int j = 0; j < CB; j++)
        Bb[j] = Bt + (size_t)(bn + (wave * CB + j) * 16 + rr) * K + kbeg + cc;

    // frag read: row ml of chunk, k-seg quad at swizzled slot
    const int fslot = ((quad + (ml >> 1)) & 3) * 8;

    // preload tile 0 into buffer 0
#pragma unroll
    for (int j = 0; j < CA; j++)
        load_lds16(Aa[j], &As[0][(wave * CA + j) * 512]);
#pragma unroll
    for (int j = 0; j < CB; j++)
        load_lds16(Bb[j], &Bs[0][(wave * CB + j) * 512]);
    __syncthreads();

    const int steps = Kslice >> 5;
    for (int s = 0; s < steps; s++) {
        const int cur = s & 1, nxt = cur ^ 1;
        const bool more = (s + 1 < steps);
        if (more) {                           // async-stage tile s+1 -> buf nxt
            const int k0 = (s + 1) * 32;
#pragma unroll
            for (int j = 0; j < CA; j++)
                load_lds16(Aa[j] + k0, &As[nxt][(wave * CA + j) * 512]);
#pragma unroll
            for (int j = 0; j < CB; j++)
                load_lds16(Bb[j] + k0, &Bs[nxt][(wave * CB + j) * 512]);
        }

        bf16x8 af[4], bfr[FN];
#pragma unroll
        for (int i = 0; i < 4; i++)
            af[i] = *(const bf16x8*)&As[cur][(wm + i * 16 + ml) * 32 + fslot];
#pragma unroll
        for (int j = 0; j < FN; j++)
            bfr[j] = *(const bf16x8*)&Bs[cur][(wn + j * 16 + ml) * 32 + fslot];

#pragma unroll
        for (int i = 0; i < 4; i++)
#pragma unroll
            for (int j = 0; j < FN; j++)
                acc[i][j] = __builtin_amdgcn_mfma_f32_16x16x32_bf16(
                    af[i], bfr[j], acc[i][j], 0, 0, 0);

        if (more) __syncthreads();            // drains async loads (vmcnt 0)
    }

    unsigned short* op = outp + (size_t)blockIdx.z * zstride;
#pragma unroll
    for (int i = 0; i < 4; i++)
#pragma unroll
        for (int j = 0; j < FN; j++)
#pragma unroll
            for (int r = 0; r < 4; r++) {
                const int row = bm + wm + i * 16 + quad * 4 + r;  // C/D row=quad*4+reg
                const int col = bn + wn + j * 16 + ml;            // C/D col=lane&15
                const float v = acc[i][j][r];
                if (EPI == 0) {
                    op[(size_t)row * N + col] = f2b(v);
                } else if (EPI == 2) {
                    const float u = v + bias[col];
                    const float g = 0.5f * u * (1.0f + erff(u * 0.70710678118654752f));
                    outb[(size_t)row * N + col] = f2b(g);
                } else {
                    // split qkv: col -> (which, head, dim); head-major bf16
                    const int which = col >> 9;
                    const int hh = (col & 511) >> 6;
                    const int dim = col & 63;
                    unsigned short* dst =
                        which == 0 ? outq : (which == 1 ? outk : outv);
                    dst[((size_t)hh * MROWS + row) * HD + dim] = f2b(v);
                }
            }
}

// ---------------------------------------------------------------------------
// Split-K reduce (bf16 partials) + residual + bias, optionally fused with the
// NEXT LayerNorm:  x' = xin + sum_z part[z] + bias;
//                  if DO_LN: h = LN(x')*lns + lnb (bf16)
// One wave per row. Deterministic f32 sum order; in-place xout==xin safe.
// ---------------------------------------------------------------------------
template<bool DO_LN>
__global__ __launch_bounds__(256) void reduce_kernel(
    const float* __restrict__ xin,
    const unsigned short* __restrict__ part,   // [4][MROWS x DM] bf16
    const float* __restrict__ bias,            // DM
    const float* __restrict__ lns, const float* __restrict__ lnb,
    float* __restrict__ xout, unsigned short* __restrict__ h)
{
    const int wid  = blockIdx.x * 4 + (threadIdx.x >> 6);
    const int lane = threadIdx.x & 63;
    const int c0 = lane * 4, c1 = 256 + lane * 4;
    const size_t ro = (size_t)wid * DM;

    float4 a0 = *(const float4*)&xin[ro + c0];
    float4 a1 = *(const float4*)&xin[ro + c1];
#pragma unroll
    for (int z = 0; z < 4; z++) {
        const unsigned short* p = part + (size_t)z * (MROWS * (size_t)DM) + ro;
        const ushort4 p0 = *(const ushort4*)&p[c0];
        const ushort4 p1 = *(const ushort4*)&p[c1];
        a0.x += b2f(p0.x); a0.y += b2f(p0.y); a0.z += b2f(p0.z); a0.w += b2f(p0.w);
        a1.x += b2f(p1.x); a1.y += b2f(p1.y); a1.z += b2f(p1.z); a1.w += b2f(p1.w);
    }
    a0.x += bias[c0+0]; a0.y += bias[c0+1]; a0.z += bias[c0+2]; a0.w += bias[c0+3];
    a1.x += bias[c1+0]; a1.y += bias[c1+1]; a1.z += bias[c1+2]; a1.w += bias[c1+3];

    *(float4*)&xout[ro + c0] = a0;
    *(float4*)&xout[ro + c1] = a1;

    if (DO_LN) {
        float s = a0.x + a0.y + a0.z + a0.w + a1.x + a1.y + a1.z + a1.w;
        float q = a0.x*a0.x + a0.y*a0.y + a0.z*a0.z + a0.w*a0.w
                + a1.x*a1.x + a1.y*a1.y + a1.z*a1.z + a1.w*a1.w;
#pragma unroll
        for (int off = 32; off; off >>= 1) {
            s += __shfl_xor(s, off, 64);
            q += __shfl_xor(q, off, 64);
        }
        const float mean = s * (1.0f / DM);
        const float var  = q * (1.0f / DM) - mean * mean;
        const float rs   = rsqrtf(var + 1e-5f);
        unsigned short* hr = h + ro;
        ushort4 o0, o1;
        o0.x = f2b((a0.x - mean) * rs * lns[c0+0] + lnb[c0+0]);
        o0.y = f2b((a0.y - mean) * rs * lns[c0+1] + lnb[c0+1]);
        o0.z = f2b((a0.z - mean) * rs * lns[c0+2] + lnb[c0+2]);
        o0.w = f2b((a0.w - mean) * rs * lns[c0+3] + lnb[c0+3]);
        o1.x = f2b((a1.x - mean) * rs * lns[c1+0] + lnb[c1+0]);
        o1.y = f2b((a1.y - mean) * rs * lns[c1+1] + lnb[c1+1]);
        o1.z = f2b((a1.z - mean) * rs * lns[c1+2] + lnb[c1+2]);
        o1.w = f2b((a1.w - mean) * rs * lns[c1+3] + lnb[c1+3]);
        *(ushort4*)&hr[c0] = o0;
        *(ushort4*)&hr[c1] = o1;
    }
}

// ---------------------------------------------------------------------------
extern "C" void kernel_launch(void* const* d_in, const int* in_sizes, int n_in,
                              void* d_out, int out_size, void* d_ws, size_t ws_size,
                              hipStream_t stream)
{
    (void)in_sizes; (void)n_in; (void)out_size; (void)ws_size;
    const float* x_in   = (const float*)d_in[0];
    const float* ln1_s  = (const float*)d_in[1];
    const float* ln1_b  = (const float*)d_in[2];
    const float* qkv_w  = (const float*)d_in[3];
    const float* proj_w = (const float*)d_in[4];
    const float* proj_b = (const float*)d_in[5];
    const float* ln2_s  = (const float*)d_in[6];
    const float* ln2_b  = (const float*)d_in[7];
    const float* w1     = (const float*)d_in[8];
    const float* b1     = (const float*)d_in[9];
    const float* w2     = (const float*)d_in[10];
    const float* b2     = (const float*)d_in[11];

    // Workspace carve-up (bytes)
    char* ws = (char*)d_ws;
    float*          xbuf = (float*)(ws);                        //   0 MB, 8 MB
    unsigned short* qhb  = (unsigned short*)(ws + 8388608);     //   8 MB, 4 MB bf16 [8][4096][64]
    unsigned short* khb  = (unsigned short*)(ws + 12582912);    //  12 MB, 4 MB
    unsigned short* vhb  = (unsigned short*)(ws + 16777216);    //  16 MB, 4 MB
    unsigned short* ubuf = (unsigned short*)(ws + 33554432);    //  32 MB, 16 MB bf16
    unsigned short* hbuf = (unsigned short*)(ws + 50331648);    //  48 MB, 4 MB
    unsigned short* obuf = (unsigned short*)(ws + 54525952);    //  52 MB, 4 MB
    unsigned short* part = (unsigned short*)(ws + 58720256);    //  56 MB, 16 MB bf16 [4][4096x512]
    unsigned short* qkvT = (unsigned short*)(ws + 92274688);    //  88 MB
    unsigned short* projT= (unsigned short*)(ws + 96993280);
    unsigned short* w1T  = (unsigned short*)(ws + 98566144);
    unsigned short* w2T  = (unsigned short*)(ws + 104857600);   // ends 106 MB

    const size_t ZS = (size_t)MROWS * DM;   // partial-slice stride (elements)

    hipMemcpyAsync(xbuf, x_in, (size_t)MROWS * DM * sizeof(float),
                   hipMemcpyDeviceToDevice, stream);

    transpose_w_kernel<<<dim3(1536/32, 512/32, 3),  dim3(32, 8), 0, stream>>>(qkv_w,  qkvT, 512, 1536);
    transpose_w_kernel<<<dim3( 512/32, 512/32, 3),  dim3(32, 8), 0, stream>>>(proj_w, projT, 512, 512);
    transpose_w_kernel<<<dim3(2048/32, 512/32, 3),  dim3(32, 8), 0, stream>>>(w1,     w1T,  512, 2048);
    transpose_w_kernel<<<dim3( 512/32, 2048/32, 3), dim3(32, 8), 0, stream>>>(w2,     w2T, 2048, 512);

    // depth-0 LN1 (later LNs fused into reduce_kernel)
    ln_kernel<<<MROWS / 4, 256, 0, stream>>>(xbuf, ln1_s, ln1_b, hbuf);

    for (int d = 0; d < NDEPTH; d++) {
        const int dil = 1 << d;

        // qkv = h @ qkv_w -> head-major bf16 q/k/v. grid (24,32) = 768 blocks.
        gemm_kernel<3, 64><<<dim3(1536/64, MROWS/128, 1), 256, 0, stream>>>(
            hbuf, qkvT + (size_t)d * 1536 * 512, nullptr, nullptr, nullptr,
            qhb, khb, vhb, 1536, 512, 512, 0);
        // dilated attention -> o (bf16)
        attn_kernel<<<2 * NH * (TSEQ / 16), 256, 0, stream>>>(qhb, khb, vhb, obuf, dil);
        // proj partials (bf16): split-K x4, Kslice 128. grid (8,32,4) = 1024 blocks.
        gemm_kernel<0, 64><<<dim3(512/64, MROWS/128, 4), 256, 0, stream>>>(
            obuf, projT + (size_t)d * 512 * 512, nullptr, part, nullptr,
            nullptr, nullptr, nullptr, 512, 512, 128, ZS);
        // x += sum(part) + proj_b ; h = LN2(x) fused
        reduce_kernel<true><<<MROWS / 4, 256, 0, stream>>>(
            xbuf, part, proj_b + d * DM, ln2_s + d * DM, ln2_b + d * DM,
            xbuf, hbuf);
        // u = gelu(h @ w1 + b1). TN=128: grid (16,32) = 512 blocks, 8 waves/CU.
        gemm_kernel<2, 128><<<dim3(2048/128, MROWS/128, 1), 256, 0, stream>>>(
            hbuf, w1T + (size_t)d * 2048 * 512, b1 + d * 2048, nullptr, ubuf,
            nullptr, nullptr, nullptr, 2048, 512, 512, 0);
        // w2 partials (bf16): split-K x4, Kslice 512. TN=128: grid (4,32,4) = 512.
        gemm_kernel<0, 128><<<dim3(512/128, MROWS/128, 4), 256, 0, stream>>>(
            ubuf, w2T + (size_t)d * 512 * 2048, nullptr, part, nullptr,
            nullptr, nullptr, nullptr, 512, 2048, 512, ZS);
        // x += sum(part) + b2 ; fuse next depth's LN1 (or final write to d_out)
        if (d < NDEPTH - 1) {
            reduce_kernel<true><<<MROWS / 4, 256, 0, stream>>>(
                xbuf, part, b2 + d * DM, ln1_s + (d+1) * DM, ln1_b + (d+1) * DM,
                xbuf, hbuf);
        } else {
            reduce_kernel<false><<<MROWS / 4, 256, 0, stream>>>(
                xbuf, part, b2 + d * DM, nullptr, nullptr,
                (float*)d_out, nullptr);
        }
    }
}

// Round 13
// 387.330 us; speedup vs baseline: 2.0391x; 1.0496x over previous
//
#include <hip/hip_runtime.h>
#include <math.h>

// Problem constants (B=2, T=2048, D=512, H=8, hd=64, K=16, DEPTH=3)
#define TSEQ   2048
#define DM     512
#define NH     8
#define HD     64
#define KATT   16
#define NDEPTH 3
#define MROWS  4096   // B*T

typedef __attribute__((ext_vector_type(8))) short bf16x8;
typedef __attribute__((ext_vector_type(8))) unsigned short u16x8;
typedef __attribute__((ext_vector_type(4))) float f32x4;

// f32 -> bf16 (round-to-nearest-even), bit-level
static __device__ __forceinline__ unsigned short f2b(float f) {
    unsigned int u = __float_as_uint(f);
    unsigned int r = (u + 0x7fffu + ((u >> 16) & 1u)) >> 16;
    return (unsigned short)r;
}
// bf16 bits -> f32
static __device__ __forceinline__ float b2f(unsigned short s) {
    return __uint_as_float((unsigned int)s << 16);
}

// global -> LDS direct DMA, 16 B per lane; HW writes lane i at lds + i*16.
static __device__ __forceinline__ void load_lds16(const void* g, void* l) {
    __builtin_amdgcn_global_load_lds(
        (const __attribute__((address_space(1))) unsigned int*)g,
        (__attribute__((address_space(3))) unsigned int*)l, 16, 0, 0);
}

// ---------------------------------------------------------------------------
// Weight prep, ALL weights in ONE launch: W f32 [K x N] (x3 depth) -> bf16
// [N x K]. Flat block-id decode over 32x32 tiles:
//   qkv 48x16x3=2304 | proj 16x16x3=768 | w1 64x16x3=3072 | w2 16x64x3=3072
// ---------------------------------------------------------------------------
__global__ __launch_bounds__(256) void transpose_all_kernel(
    const float* __restrict__ qkv_w, const float* __restrict__ proj_w,
    const float* __restrict__ w1,    const float* __restrict__ w2,
    unsigned short* __restrict__ qkvT, unsigned short* __restrict__ projT,
    unsigned short* __restrict__ w1T,  unsigned short* __restrict__ w2T)
{
    int id = blockIdx.x;
    const float* W; unsigned short* Wt; int Kd, Nd;
    if (id < 2304)      { W = qkv_w;  Wt = qkvT;  Kd = 512;  Nd = 1536; }
    else if (id < 3072) { W = proj_w; Wt = projT; Kd = 512;  Nd = 512;  id -= 2304; }
    else if (id < 6144) { W = w1;     Wt = w1T;   Kd = 512;  Nd = 2048; id -= 3072; }
    else                { W = w2;     Wt = w2T;   Kd = 2048; Nd = 512;  id -= 6144; }
    const int nt = Nd >> 5, per = nt * (Kd >> 5);
    const int d = id / per, rem = id % per;
    const int k0 = (rem / nt) * 32, n0 = (rem % nt) * 32;

    __shared__ float tile[32][33];
    const size_t off = (size_t)d * Kd * Nd;
    const float* Wd = W + off;
    unsigned short* Wtd = Wt + off;
    const int tx = threadIdx.x, ty = threadIdx.y;
#pragma unroll
    for (int r = 0; r < 32; r += 8)
        tile[ty + r][tx] = Wd[(size_t)(k0 + ty + r) * Nd + (n0 + tx)];
    __syncthreads();
#pragma unroll
    for (int r = 0; r < 32; r += 8)
        Wtd[(size_t)(n0 + ty + r) * Kd + (k0 + tx)] = f2b(tile[tx][ty + r]);
}

// ---------------------------------------------------------------------------
// LayerNorm: x f32 [4096 x 512] -> h bf16 [4096 x 512]. One wave per row.
// (only used for depth-0 LN1; later LNs are fused into reduce_kernel)
// ---------------------------------------------------------------------------
__global__ __launch_bounds__(256) void ln_kernel(
    const float* __restrict__ x, const float* __restrict__ sc,
    const float* __restrict__ bi, unsigned short* __restrict__ h)
{
    const int wid  = blockIdx.x * 4 + (threadIdx.x >> 6);
    const int lane = threadIdx.x & 63;
    const float* xr = x + (size_t)wid * DM;
    const float4 v0 = *(const float4*)&xr[lane * 4];
    const float4 v1 = *(const float4*)&xr[256 + lane * 4];
    float s = v0.x + v0.y + v0.z + v0.w + v1.x + v1.y + v1.z + v1.w;
    float q = v0.x*v0.x + v0.y*v0.y + v0.z*v0.z + v0.w*v0.w
            + v1.x*v1.x + v1.y*v1.y + v1.z*v1.z + v1.w*v1.w;
#pragma unroll
    for (int off = 32; off; off >>= 1) {
        s += __shfl_xor(s, off, 64);
        q += __shfl_xor(q, off, 64);
    }
    const float mean = s * (1.0f / DM);
    const float var  = q * (1.0f / DM) - mean * mean;
    const float rs   = rsqrtf(var + 1e-5f);
    unsigned short* hr = h + (size_t)wid * DM;
    const int c0 = lane * 4, c1 = 256 + lane * 4;
    ushort4 o0, o1;
    o0.x = f2b((v0.x - mean) * rs * sc[c0+0] + bi[c0+0]);
    o0.y = f2b((v0.y - mean) * rs * sc[c0+1] + bi[c0+1]);
    o0.z = f2b((v0.z - mean) * rs * sc[c0+2] + bi[c0+2]);
    o0.w = f2b((v0.w - mean) * rs * sc[c0+3] + bi[c0+3]);
    o1.x = f2b((v1.x - mean) * rs * sc[c1+0] + bi[c1+0]);
    o1.y = f2b((v1.y - mean) * rs * sc[c1+1] + bi[c1+1]);
    o1.z = f2b((v1.z - mean) * rs * sc[c1+2] + bi[c1+2]);
    o1.w = f2b((v1.w - mean) * rs * sc[c1+3] + bi[c1+3]);
    *(ushort4*)&hr[c0] = o0;
    *(ushort4*)&hr[c1] = o1;
}

// ---------------------------------------------------------------------------
// Dilated attention over head-major bf16 q/k/v slabs (R6 design, proven).
// ---------------------------------------------------------------------------
__global__ __launch_bounds__(256) void attn_kernel(
    const unsigned short* __restrict__ qh, const unsigned short* __restrict__ kh,
    const unsigned short* __restrict__ vh, unsigned short* __restrict__ o, int dil)
{
    const int blk  = blockIdx.x;
    const int tile = blk & (TSEQ / 16 - 1);   // 128 query tiles
    const int bh   = blk >> 7;
    const int b    = bh >> 3, hh = bh & 7;
    const int t0   = tile * 16;
    const int wave = threadIdx.x >> 6, lane = threadIdx.x & 63;
    const int tq   = wave * 4 + (lane >> 4);  // query 0..15
    const int s    = lane & 15;               // key slot 0..15
    const int t    = t0 + tq;
    const size_t slab = ((size_t)hh * MROWS + (size_t)b * TSEQ) * HD;

    __shared__ float p_lds[16][17];

    // ---- phase 1: scores + softmax ----
    int row = t - s * dil;
    const bool valid = (row >= 0);
    row = max(row, 0);
    const u16x8* kr = (const u16x8*)(kh + slab + (size_t)row * HD);
    const u16x8* qr = (const u16x8*)(qh + slab + (size_t)t * HD);
    float dot = 0.0f;
#pragma unroll
    for (int j = 0; j < 8; j++) {
        const u16x8 kk = kr[j];
        const u16x8 qq = qr[j];
#pragma unroll
        for (int e = 0; e < 8; e++) dot += b2f(qq[e]) * b2f(kk[e]);
    }
    const float sc = valid ? dot * 0.125f : -1e30f;
    float m = sc;
#pragma unroll
    for (int off = 1; off < 16; off <<= 1) m = fmaxf(m, __shfl_xor(m, off, 64));
    const float p = expf(sc - m);
    float l = p;
#pragma unroll
    for (int off = 1; off < 16; off <<= 1) l += __shfl_xor(l, off, 64);
    p_lds[tq][s] = p / l;
    __syncthreads();

    // ---- phase 2: o = sum_s p * v (lane = dim) ----
#pragma unroll
    for (int qi = 0; qi < 4; qi++) {
        const int qq = qi * 4 + wave;
        const int tt = t0 + qq;
        float acc = 0.0f;
#pragma unroll
        for (int ss = 0; ss < KATT; ss++) {
            int vr = tt - ss * dil;
            const float pw = p_lds[qq][ss];   // exactly 0 for masked slots
            vr = max(vr, 0);
            acc += pw * b2f(vh[slab + (size_t)vr * HD + lane]);
        }
        o[(size_t)(b * TSEQ + tt) * DM + (size_t)hh * HD + lane] = f2b(acc);
    }
}

// ---------------------------------------------------------------------------
// GEMM (R11-proven): C = A_bf16[M,K] * Bt[N,K]^T over K-slice z. BK=32,
// block 128 x TN, 4 waves (2x2), wave tile 64 x TN/2. Direct global->LDS DMA
// staging (16 B/lane), unpadded 64 B rows, k-seg swizzle -> 2-way aliasing
// only. Double-buffered, ONE __syncthreads per k-step.
//   EPI 0: outp[z*zstride + idx] = bf16(C)   (proj/w2 partials, bf16)
//   EPI 2: outb = bf16(gelu(C + bias))       (w1, exact gelu)
//   EPI 3: split qkv -> head-major bf16 q/k/v slabs
// ---------------------------------------------------------------------------
template<int EPI, int TN>
__global__ __launch_bounds__(256) void gemm_kernel(
    const unsigned short* __restrict__ A,   // M x K
    const unsigned short* __restrict__ Bt,  // N x K
    const float* __restrict__ bias,         // N (EPI 2 only)
    unsigned short* __restrict__ outp,      // bf16 partials (EPI 0)
    unsigned short* __restrict__ outb,      // bf16 out (EPI 2)
    unsigned short* __restrict__ outq,      // EPI 3
    unsigned short* __restrict__ outk,      // EPI 3
    unsigned short* __restrict__ outv,      // EPI 3
    int N, int K, int Kslice, size_t zstride)
{
    constexpr int FN = TN / 32;               // B frags per wave (2 or 4)
    constexpr int CA = 2;                     // A 16-row chunks per wave
    constexpr int CB = TN / 64;               // B chunks per wave (1 or 2)
    const int tid  = threadIdx.x;
    const int wave = tid >> 6, lane = tid & 63;
    const int bm = blockIdx.y * 128;
    const int bn = blockIdx.x * TN;
    const int wm = (wave >> 1) * 64;          // wave rows: 64
    const int wn = (wave & 1) * (TN / 2);     // wave cols: TN/2
    const int ml = lane & 15, quad = lane >> 4;
    const int kbeg = blockIdx.z * Kslice;

    __shared__ unsigned short As[2][128 * 32];   // unpadded: 2 x 8 KB
    __shared__ unsigned short Bs[2][TN * 32];    // unpadded: 2 x TN*64 B

    f32x4 acc[4][FN] = {};

    // staging source: lane i=4r+s -> LDS (row r, 16B slot s) of its chunk;
    // source k-seg c with s = (c + (r>>1)) & 3  (R3-verified swizzle)
    const int rr = lane >> 2, ss = lane & 3;
    const int cc = ((ss - (rr >> 1)) & 3) * 8;   // shorts
    const unsigned short* Aa[CA];
    const unsigned short* Bb[CB];
#pragma unroll
    for (int j = 0; j < CA; j++)
        Aa[j] = A + (size_t)(bm + (wave * CA + j) * 16 + rr) * K + kbeg + cc;
#pragma unroll
    for (int j = 0; j < CB; j++)
        Bb[j] = Bt + (size_t)(bn + (wave * CB + j) * 16 + rr) * K + kbeg + cc;

    // frag read: row ml of chunk, k-seg quad at swizzled slot
    const int fslot = ((quad + (ml >> 1)) & 3) * 8;

    // preload tile 0 into buffer 0
#pragma unroll
    for (int j = 0; j < CA; j++)
        load_lds16(Aa[j], &As[0][(wave * CA + j) * 512]);
#pragma unroll
    for (int j = 0; j < CB; j++)
        load_lds16(Bb[j], &Bs[0][(wave * CB + j) * 512]);
    __syncthreads();

    const int steps = Kslice >> 5;
    for (int s = 0; s < steps; s++) {
        const int cur = s & 1, nxt = cur ^ 1;
        const bool more = (s + 1 < steps);
        if (more) {                           // async-stage tile s+1 -> buf nxt
            const int k0 = (s + 1) * 32;
#pragma unroll
            for (int j = 0; j < CA; j++)
                load_lds16(Aa[j] + k0, &As[nxt][(wave * CA + j) * 512]);
#pragma unroll
            for (int j = 0; j < CB; j++)
                load_lds16(Bb[j] + k0, &Bs[nxt][(wave * CB + j) * 512]);
        }

        bf16x8 af[4], bfr[FN];
#pragma unroll
        for (int i = 0; i < 4; i++)
            af[i] = *(const bf16x8*)&As[cur][(wm + i * 16 + ml) * 32 + fslot];
#pragma unroll
        for (int j = 0; j < FN; j++)
            bfr[j] = *(const bf16x8*)&Bs[cur][(wn + j * 16 + ml) * 32 + fslot];

#pragma unroll
        for (int i = 0; i < 4; i++)
#pragma unroll
            for (int j = 0; j < FN; j++)
                acc[i][j] = __builtin_amdgcn_mfma_f32_16x16x32_bf16(
                    af[i], bfr[j], acc[i][j], 0, 0, 0);

        if (more) __syncthreads();            // drains async loads (vmcnt 0)
    }

    unsigned short* op = outp + (size_t)blockIdx.z * zstride;
#pragma unroll
    for (int i = 0; i < 4; i++)
#pragma unroll
        for (int j = 0; j < FN; j++)
#pragma unroll
            for (int r = 0; r < 4; r++) {
                const int row = bm + wm + i * 16 + quad * 4 + r;  // C/D row=quad*4+reg
                const int col = bn + wn + j * 16 + ml;            // C/D col=lane&15
                const float v = acc[i][j][r];
                if (EPI == 0) {
                    op[(size_t)row * N + col] = f2b(v);
                } else if (EPI == 2) {
                    const float u = v + bias[col];
                    const float g = 0.5f * u * (1.0f + erff(u * 0.70710678118654752f));
                    outb[(size_t)row * N + col] = f2b(g);
                } else {
                    // split qkv: col -> (which, head, dim); head-major bf16
                    const int which = col >> 9;
                    const int hh = (col & 511) >> 6;
                    const int dim = col & 63;
                    unsigned short* dst =
                        which == 0 ? outq : (which == 1 ? outk : outv);
                    dst[((size_t)hh * MROWS + row) * HD + dim] = f2b(v);
                }
            }
}

// ---------------------------------------------------------------------------
// Split-K reduce (bf16 partials, Z slices) + residual + bias, optionally
// fused with the NEXT LayerNorm:  x' = xin + sum_z part[z] + bias;
//                  if DO_LN: h = LN(x')*lns + lnb (bf16)
// One wave per row. Deterministic f32 sum order; in-place xout==xin safe.
// ---------------------------------------------------------------------------
template<bool DO_LN, int Z>
__global__ __launch_bounds__(256) void reduce_kernel(
    const float* __restrict__ xin,
    const unsigned short* __restrict__ part,   // [Z][MROWS x DM] bf16
    const float* __restrict__ bias,            // DM
    const float* __restrict__ lns, const float* __restrict__ lnb,
    float* __restrict__ xout, unsigned short* __restrict__ h)
{
    const int wid  = blockIdx.x * 4 + (threadIdx.x >> 6);
    const int lane = threadIdx.x & 63;
    const int c0 = lane * 4, c1 = 256 + lane * 4;
    const size_t ro = (size_t)wid * DM;

    float4 a0 = *(const float4*)&xin[ro + c0];
    float4 a1 = *(const float4*)&xin[ro + c1];
#pragma unroll
    for (int z = 0; z < Z; z++) {
        const unsigned short* p = part + (size_t)z * (MROWS * (size_t)DM) + ro;
        const ushort4 p0 = *(const ushort4*)&p[c0];
        const ushort4 p1 = *(const ushort4*)&p[c1];
        a0.x += b2f(p0.x); a0.y += b2f(p0.y); a0.z += b2f(p0.z); a0.w += b2f(p0.w);
        a1.x += b2f(p1.x); a1.y += b2f(p1.y); a1.z += b2f(p1.z); a1.w += b2f(p1.w);
    }
    a0.x += bias[c0+0]; a0.y += bias[c0+1]; a0.z += bias[c0+2]; a0.w += bias[c0+3];
    a1.x += bias[c1+0]; a1.y += bias[c1+1]; a1.z += bias[c1+2]; a1.w += bias[c1+3];

    *(float4*)&xout[ro + c0] = a0;
    *(float4*)&xout[ro + c1] = a1;

    if (DO_LN) {
        float s = a0.x + a0.y + a0.z + a0.w + a1.x + a1.y + a1.z + a1.w;
        float q = a0.x*a0.x + a0.y*a0.y + a0.z*a0.z + a0.w*a0.w
                + a1.x*a1.x + a1.y*a1.y + a1.z*a1.z + a1.w*a1.w;
#pragma unroll
        for (int off = 32; off; off >>= 1) {
            s += __shfl_xor(s, off, 64);
            q += __shfl_xor(q, off, 64);
        }
        const float mean = s * (1.0f / DM);
        const float var  = q * (1.0f / DM) - mean * mean;
        const float rs   = rsqrtf(var + 1e-5f);
        unsigned short* hr = h + ro;
        ushort4 o0, o1;
        o0.x = f2b((a0.x - mean) * rs * lns[c0+0] + lnb[c0+0]);
        o0.y = f2b((a0.y - mean) * rs * lns[c0+1] + lnb[c0+1]);
        o0.z = f2b((a0.z - mean) * rs * lns[c0+2] + lnb[c0+2]);
        o0.w = f2b((a0.w - mean) * rs * lns[c0+3] + lnb[c0+3]);
        o1.x = f2b((a1.x - mean) * rs * lns[c1+0] + lnb[c1+0]);
        o1.y = f2b((a1.y - mean) * rs * lns[c1+1] + lnb[c1+1]);
        o1.z = f2b((a1.z - mean) * rs * lns[c1+2] + lnb[c1+2]);
        o1.w = f2b((a1.w - mean) * rs * lns[c1+3] + lnb[c1+3]);
        *(ushort4*)&hr[c0] = o0;
        *(ushort4*)&hr[c1] = o1;
    }
}

// ---------------------------------------------------------------------------
extern "C" void kernel_launch(void* const* d_in, const int* in_sizes, int n_in,
                              void* d_out, int out_size, void* d_ws, size_t ws_size,
                              hipStream_t stream)
{
    (void)in_sizes; (void)n_in; (void)out_size; (void)ws_size;
    const float* x_in   = (const float*)d_in[0];
    const float* ln1_s  = (const float*)d_in[1];
    const float* ln1_b  = (const float*)d_in[2];
    const float* qkv_w  = (const float*)d_in[3];
    const float* proj_w = (const float*)d_in[4];
    const float* proj_b = (const float*)d_in[5];
    const float* ln2_s  = (const float*)d_in[6];
    const float* ln2_b  = (const float*)d_in[7];
    const float* w1     = (const float*)d_in[8];
    const float* b1     = (const float*)d_in[9];
    const float* w2     = (const float*)d_in[10];
    const float* b2     = (const float*)d_in[11];

    // Workspace carve-up (bytes)
    char* ws = (char*)d_ws;
    float*          xbuf = (float*)(ws);                        //   0 MB, 8 MB
    unsigned short* qhb  = (unsigned short*)(ws + 8388608);     //   8 MB, 4 MB bf16 [8][4096][64]
    unsigned short* khb  = (unsigned short*)(ws + 12582912);    //  12 MB, 4 MB
    unsigned short* vhb  = (unsigned short*)(ws + 16777216);    //  16 MB, 4 MB
    unsigned short* ubuf = (unsigned short*)(ws + 33554432);    //  32 MB, 16 MB bf16
    unsigned short* hbuf = (unsigned short*)(ws + 50331648);    //  48 MB, 4 MB
    unsigned short* obuf = (unsigned short*)(ws + 54525952);    //  52 MB, 4 MB
    unsigned short* part = (unsigned short*)(ws + 58720256);    //  56 MB, 16 MB bf16 [4][4096x512]
    unsigned short* qkvT = (unsigned short*)(ws + 92274688);    //  88 MB
    unsigned short* projT= (unsigned short*)(ws + 96993280);
    unsigned short* w1T  = (unsigned short*)(ws + 98566144);
    unsigned short* w2T  = (unsigned short*)(ws + 104857600);   // ends 106 MB

    const size_t ZS = (size_t)MROWS * DM;   // partial-slice stride (elements)

    // All weight transposes in one launch (9216 tiles; no x memcpy needed).
    transpose_all_kernel<<<9216, dim3(32, 8), 0, stream>>>(
        qkv_w, proj_w, w1, w2, qkvT, projT, w1T, w2T);

    // depth-0 LN1 reads pristine x_in directly
    ln_kernel<<<MROWS / 4, 256, 0, stream>>>(x_in, ln1_s, ln1_b, hbuf);

    for (int d = 0; d < NDEPTH; d++) {
        const int dil = 1 << d;
        const float* xin = (d == 0) ? x_in : xbuf;   // x residual source

        // qkv = h @ qkv_w -> head-major bf16 q/k/v. grid (24,32) = 768 blocks.
        gemm_kernel<3, 64><<<dim3(1536/64, MROWS/128, 1), 256, 0, stream>>>(
            hbuf, qkvT + (size_t)d * 1536 * 512, nullptr, nullptr, nullptr,
            qhb, khb, vhb, 1536, 512, 512, 0);
        // dilated attention -> o (bf16)
        attn_kernel<<<2 * NH * (TSEQ / 16), 256, 0, stream>>>(qhb, khb, vhb, obuf, dil);
        // proj partials (bf16): split-K x2, Kslice 256. grid (8,32,2) = 512 blocks.
        gemm_kernel<0, 64><<<dim3(512/64, MROWS/128, 2), 256, 0, stream>>>(
            obuf, projT + (size_t)d * 512 * 512, nullptr, part, nullptr,
            nullptr, nullptr, nullptr, 512, 512, 256, ZS);
        // x = xin + sum(part) + proj_b ; h = LN2(x) fused
        reduce_kernel<true, 2><<<MROWS / 4, 256, 0, stream>>>(
            xin, part, proj_b + d * DM, ln2_s + d * DM, ln2_b + d * DM,
            xbuf, hbuf);
        // u = gelu(h @ w1 + b1). TN=128: grid (16,32) = 512 blocks.
        gemm_kernel<2, 128><<<dim3(2048/128, MROWS/128, 1), 256, 0, stream>>>(
            hbuf, w1T + (size_t)d * 2048 * 512, b1 + d * 2048, nullptr, ubuf,
            nullptr, nullptr, nullptr, 2048, 512, 512, 0);
        // w2 partials (bf16): split-K x4, Kslice 512. TN=128: grid (4,32,4) = 512.
        gemm_kernel<0, 128><<<dim3(512/128, MROWS/128, 4), 256, 0, stream>>>(
            ubuf, w2T + (size_t)d * 512 * 2048, nullptr, part, nullptr,
            nullptr, nullptr, nullptr, 512, 2048, 512, ZS);
        // x += sum(part) + b2 ; fuse next depth's LN1 (or final write to d_out)
        if (d < NDEPTH - 1) {
            reduce_kernel<true, 4><<<MROWS / 4, 256, 0, stream>>>(
                xbuf, part, b2 + d * DM, ln1_s + (d+1) * DM, ln1_b + (d+1) * DM,
                xbuf, hbuf);
        } else {
            reduce_kernel<false, 4><<<MROWS / 4, 256, 0, stream>>>(
                xbuf, part, b2 + d * DM, nullptr, nullptr,
                (float*)d_out, nullptr);
        }
    }
}